// Round 11
// baseline (221.585 us; speedup 1.0000x reference)
//
#include <hip/hip_runtime.h>

#define N_NODES 50000
#define N_EDGES 800000
#define DIM 128
#define N_REL 86
#define BATCH 2048
#define CAP 64               // per-node bucket capacity; max deg ~45 for Poisson(16)
#define ZROW N_NODES         // sentinel row: zeroed embedding row, dv[ZROW]=0 (fits u16)

#define NP 196               // partitions by dst>>8 (256 nodes each; ceil(50000/256))
#define EB 196               // edge blocks for build (4096 edges each)
#define BCAP 56              // per-(block,bin) sub-bucket capacity; P(Poisson(20.9)>56)~4e-11

#define NSLAB 2              // 64-dim slabs; slab-major planes, 6.4 MB each
#define PSTR ((size_t)(N_NODES + 1) * 64)                       // ushorts per slab plane

using bf16x8 = __attribute__((ext_vector_type(8))) short;
using f32x4  = __attribute__((ext_vector_type(4))) float;

// float -> bf16 round-to-nearest-even (finite inputs)
static __device__ __forceinline__ unsigned short f2bf(float f) {
  union { float f; unsigned int i; } v; v.f = f;
  unsigned int x = v.i;
  unsigned int r = x + 0x7FFFu + ((x >> 16) & 1u);
  return (unsigned short)(r >> 16);
}
static __device__ __forceinline__ float bf2f(unsigned short u) {
  union { unsigned int i; float f; } v;
  v.i = ((unsigned int)u) << 16;
  return v.f;
}

#define G_TQ    172           // 86 relations x 2 d-blocks
#define G_GEMM  391           // ceil(50000/128)
#define TPAD 136              // 128+8 bf16: 272 B row stride -> 2-way bank alias (free)
#define QPAD 136
#define APAD 136

// ---------------- kernel 0: weight prep + sentinel zeroing + mask/Mcount zero ----------------

__global__ __launch_bounds__(256) void k_prep(const float* __restrict__ W1, const float* __restrict__ W2,
                                              const float* __restrict__ M,
                                              unsigned short* __restrict__ W1th, unsigned short* __restrict__ W1tl,
                                              unsigned short* __restrict__ W2th, unsigned short* __restrict__ W2tl,
                                              unsigned short* __restrict__ Mth,
                                              unsigned short* __restrict__ hs,
                                              unsigned short* __restrict__ hbuf2,
                                              float* __restrict__ dv,
                                              int* __restrict__ mask,
                                              int* __restrict__ Mcount) {
  int g = blockIdx.x * 256 + threadIdx.x;          // 16384 threads = DIM*DIM
  #pragma unroll
  for (int q = 0; q < 4; ++q) {                    // zero needed-mask (N+1 entries)
    int idx = g + q * 16384;
    if (idx <= N_NODES) mask[idx] = 0;
  }
  // zero sentinel rows (gather pads resolve to ZROW; must be 0.0 not garbage/NaN)
  if (g < 32) {                                    // 2 slab planes x 16 ushort4
    ushort4 z = {0, 0, 0, 0};
    ((ushort4*)(hs + (size_t)(g >> 4) * PSTR))[(size_t)ZROW * 16 + (g & 15)] = z;
  }
  if (g >= 32 && g < 64) {                         // hbuf2 row (32 ushort4)
    ushort4 z = {0, 0, 0, 0};
    ((ushort4*)hbuf2)[(size_t)ZROW * 32 + (g - 32)] = z;
  }
  if (g == 64) dv[ZROW] = 0.f;
  if (g == 65) *Mcount = 0;
  int k = g >> 7, n = g & 127;
  int t = n * DIM + k;
  float w1 = W1[g];
  unsigned short h1 = f2bf(w1);
  W1th[t] = h1;
  W1tl[t] = f2bf(w1 - bf2f(h1));
  float w2 = W2[g];
  unsigned short h2 = f2bf(w2);
  W2th[t] = h2;
  W2tl[t] = f2bf(w2 - bf2f(h2));
  Mth[t] = f2bf(M[g]);
}

// ---------------- mega1: ONE-PASS edge scatter (fixed per-(block,bin) sub-buckets)
//                         ||  decoder TQ  ||  gemm1 (slab-major out) ----------------
// pe2 layout: [bin][block][BCAP]; pcntBlk[block][bin] = count (clamp at build)
// pe entry: (dst & 255) << 17 | src     (src < 50000 < 2^17)

__global__ __launch_bounds__(256) void k_mega1(const int* __restrict__ src, const int* __restrict__ dst,
                                               unsigned int* __restrict__ pe2,
                                               unsigned int* __restrict__ pcntBlk,
                                               const float* __restrict__ Rel,
                                               const unsigned short* __restrict__ Mth,
                                               unsigned short* __restrict__ Qbf,
                                               const float* __restrict__ x,
                                               const unsigned short* __restrict__ W1th,
                                               const unsigned short* __restrict__ W1tl,
                                               unsigned short* __restrict__ hs) {
  __shared__ __align__(16) unsigned char smem[64 * TPAD * 2];   // max(cur 784B, Ts 17408B)
  int bid = blockIdx.x;
  union U { uint4 u; bf16x8 h; };

  if (bid < EB) {
    unsigned int* cur = (unsigned int*)smem;
    int t = threadIdx.x;
    if (t < NP) cur[t] = 0u;
    __syncthreads();
    #pragma unroll
    for (int j = 0; j < 4; ++j) {
      int i0 = bid * 4096 + j * 1024 + t * 4;
      if (i0 < N_EDGES) {
        int4 s4 = *(const int4*)(src + i0);
        int4 d4 = *(const int4*)(dst + i0);
        int b0 = d4.x >> 8, b1 = d4.y >> 8, b2 = d4.z >> 8, b3 = d4.w >> 8;
        unsigned int p0 = atomicAdd(&cur[b0], 1u);
        unsigned int p1 = atomicAdd(&cur[b1], 1u);
        unsigned int p2 = atomicAdd(&cur[b2], 1u);
        unsigned int p3 = atomicAdd(&cur[b3], 1u);
        if (p0 < BCAP) pe2[((size_t)b0 * EB + bid) * BCAP + p0] = ((unsigned)(d4.x & 255) << 17) | (unsigned)s4.x;
        if (p1 < BCAP) pe2[((size_t)b1 * EB + bid) * BCAP + p1] = ((unsigned)(d4.y & 255) << 17) | (unsigned)s4.y;
        if (p2 < BCAP) pe2[((size_t)b2 * EB + bid) * BCAP + p2] = ((unsigned)(d4.z & 255) << 17) | (unsigned)s4.z;
        if (p3 < BCAP) pe2[((size_t)b3 * EB + bid) * BCAP + p3] = ((unsigned)(d4.w & 255) << 17) | (unsigned)s4.w;
      }
    }
    __syncthreads();
    if (t < NP) pcntBlk[bid * NP + t] = cur[t];
    return;
  }

  int wave = threadIdx.x >> 6, lane = threadIdx.x & 63;
  int l15 = lane & 15, quad = lane >> 4;

  if (bid < EB + G_TQ) {
    // ---- decoder precompute: T_r = Rel_r @ M (LDS), Q_r = T_r @ Rel_r^T ----
    unsigned short* Ts = (unsigned short*)smem;
    int tb = bid - EB;                       // [0, 172)
    int r = tb >> 1, dblk = tb & 1;
    const float* Rr = Rel + (size_t)r * DIM * DIM;
    unsigned short* Qr = Qbf + (size_t)r * DIM * DIM;
    int dw = dblk * 64 + wave * 16;
    f32x4 acc[8];
    #pragma unroll
    for (int nt = 0; nt < 8; ++nt) acc[nt] = f32x4{0.f, 0.f, 0.f, 0.f};
    #pragma unroll
    for (int ks = 0; ks < 4; ++ks) {
      int k0 = ks * 32 + quad * 8;
      const float* ap = Rr + (size_t)(dw + l15) * DIM + k0;
      float av[8];
      *(float4*)(av)     = *(const float4*)(ap);
      *(float4*)(av + 4) = *(const float4*)(ap + 4);
      bf16x8 a;
      #pragma unroll
      for (int j = 0; j < 8; ++j) a[j] = (short)f2bf(av[j]);
      #pragma unroll
      for (int nt = 0; nt < 8; ++nt) {
        U b; b.u = *(const uint4*)(Mth + (nt * 16 + l15) * DIM + k0);
        acc[nt] = __builtin_amdgcn_mfma_f32_16x16x32_bf16(a, b.h, acc[nt], 0, 0, 0);
      }
    }
    #pragma unroll
    for (int nt = 0; nt < 8; ++nt)
      #pragma unroll
      for (int reg = 0; reg < 4; ++reg)
        Ts[(wave * 16 + quad * 4 + reg) * TPAD + nt * 16 + l15] = f2bf(acc[nt][reg]);
    __syncthreads();
    f32x4 qacc[8];
    #pragma unroll
    for (int nt = 0; nt < 8; ++nt) qacc[nt] = f32x4{0.f, 0.f, 0.f, 0.f};
    #pragma unroll
    for (int ks = 0; ks < 4; ++ks) {
      int k0 = ks * 32 + quad * 8;
      U a; a.u = *(const uint4*)(Ts + (wave * 16 + l15) * TPAD + k0);
      #pragma unroll
      for (int nt = 0; nt < 8; ++nt) {
        const float* bp = Rr + (size_t)(nt * 16 + l15) * DIM + k0;
        float bv[8];
        *(float4*)(bv)     = *(const float4*)(bp);
        *(float4*)(bv + 4) = *(const float4*)(bp + 4);
        bf16x8 b;
        #pragma unroll
        for (int j = 0; j < 8; ++j) b[j] = (short)f2bf(bv[j]);
        qacc[nt] = __builtin_amdgcn_mfma_f32_16x16x32_bf16(a.h, b, qacc[nt], 0, 0, 0);
      }
    }
    #pragma unroll
    for (int nt = 0; nt < 8; ++nt)
      #pragma unroll
      for (int reg = 0; reg < 4; ++reg)
        Qr[(size_t)(dw + quad * 4 + reg) * DIM + nt * 16 + l15] = f2bf(qacc[nt][reg]);
    return;
  }

  // ---- node GEMM layer 1: hs = slab-major(x @ W1) (hi/lo 3-term, bf16 out) ----
  int r0 = (bid - EB - G_TQ) * 128 + wave * 32;
  f32x4 acc[2][8];
  #pragma unroll
  for (int mt = 0; mt < 2; ++mt)
    #pragma unroll
    for (int nt = 0; nt < 8; ++nt) acc[mt][nt] = f32x4{0.f, 0.f, 0.f, 0.f};
  #pragma unroll
  for (int ks = 0; ks < 4; ++ks) {
    int k0 = ks * 32 + quad * 8;
    bf16x8 ah[2], al[2];
    #pragma unroll
    for (int mt = 0; mt < 2; ++mt) {
      int row = r0 + mt * 16 + l15;
      row = (row < N_NODES) ? row : (N_NODES - 1);
      const float* xp = x + (size_t)row * DIM + k0;
      float xv[8];
      *(float4*)(xv)     = *(const float4*)(xp);
      *(float4*)(xv + 4) = *(const float4*)(xp + 4);
      #pragma unroll
      for (int j = 0; j < 8; ++j) {
        unsigned short h = f2bf(xv[j]);
        ah[mt][j] = (short)h;
        al[mt][j] = (short)f2bf(xv[j] - bf2f(h));
      }
    }
    #pragma unroll
    for (int nt = 0; nt < 8; ++nt) {
      U bh, bl;
      bh.u = *(const uint4*)(W1th + (nt * 16 + l15) * DIM + k0);
      bl.u = *(const uint4*)(W1tl + (nt * 16 + l15) * DIM + k0);
      #pragma unroll
      for (int mt = 0; mt < 2; ++mt) {
        acc[mt][nt] = __builtin_amdgcn_mfma_f32_16x16x32_bf16(ah[mt], bh.h, acc[mt][nt], 0, 0, 0);
        acc[mt][nt] = __builtin_amdgcn_mfma_f32_16x16x32_bf16(al[mt], bh.h, acc[mt][nt], 0, 0, 0);
        acc[mt][nt] = __builtin_amdgcn_mfma_f32_16x16x32_bf16(ah[mt], bl.h, acc[mt][nt], 0, 0, 0);
      }
    }
  }
  #pragma unroll
  for (int mt = 0; mt < 2; ++mt)
    #pragma unroll
    for (int reg = 0; reg < 4; ++reg) {
      int row = r0 + mt * 16 + quad * 4 + reg;
      if (row < N_NODES) {
        #pragma unroll
        for (int nt = 0; nt < 8; ++nt)
          hs[(size_t)(nt >> 2) * PSTR + (size_t)row * 64 + (nt & 3) * 16 + l15] = f2bf(acc[mt][nt][reg]);
      }
    }
}

// ---------------- build: ragged per-partition bucket fill (u16) + pad-to-8 + cnt + dinv ----------------

__global__ __launch_bounds__(256) void k_build(const unsigned int* __restrict__ pe2,
                                               const unsigned int* __restrict__ pcntBlk,
                                               unsigned short* __restrict__ esrc, int* __restrict__ cnt,
                                               float* __restrict__ dv) {
  __shared__ unsigned int c256[256];
  __shared__ unsigned short mk[EB];
  int p = blockIdx.x, t = threadIdx.x;
  c256[t] = 0u;
  if (t < EB) mk[t] = (unsigned short)min(pcntBlk[t * NP + p], (unsigned int)BCAP);
  __syncthreads();
  const unsigned int* pp = pe2 + (size_t)p * EB * BCAP;
  for (int j = t; j < EB * BCAP; j += 256) {
    int k = j / BCAP, i = j - k * BCAP;
    if (i < (int)mk[k]) {
      unsigned int e = pp[j];
      unsigned int local = e >> 17;
      unsigned int s = e & 0x1FFFFu;
      unsigned int slot = atomicAdd(&c256[local], 1u);
      int node = p * 256 + (int)local;
      if (slot < CAP) esrc[(size_t)node * CAP + slot] = (unsigned short)s;
    }
  }
  __syncthreads();
  int node = p * 256 + t;
  if (node < N_NODES) {
    int c = (int)c256[t];
    cnt[node] = c;
    dv[node] = rsqrtf((float)(c + 1));
    int padded = min((c + 7) & ~7, CAP);          // pad bucket to multiple of 8
    for (int s = c; s < padded; ++s) esrc[(size_t)node * CAP + s] = (unsigned short)ZROW;
  }
}

// ---------------- mark: needed set = batch nodes + their neighbors ----------------

__global__ __launch_bounds__(256) void k_mark(const int* __restrict__ head, const int* __restrict__ tail,
                                              const unsigned short* __restrict__ esrc,
                                              const int* __restrict__ cnt,
                                              int* __restrict__ mask) {
  int pos = blockIdx.x * 8 + (threadIdx.x >> 5);
  if (pos >= 2 * BATCH) return;
  int lane = threadIdx.x & 31;
  int node = (pos < BATCH) ? head[pos] : tail[pos - BATCH];
  if (lane == 0) mask[node] = 1;
  int deg = min(cnt[node], CAP);
  const unsigned short* eb = esrc + (size_t)node * CAP;
  if (lane < deg) mask[eb[lane]] = 1;
  if (lane + 32 < deg) mask[eb[lane + 32]] = 1;
}

// ---------------- compact: mask -> node list (unordered across blocks) ----------------

__global__ __launch_bounds__(256) void k_compact(const int* __restrict__ mask,
                                                 int* __restrict__ list,
                                                 int* __restrict__ Mcount) {
  __shared__ int sd[256];
  __shared__ int sbase;
  int node = blockIdx.x * 256 + threadIdx.x;
  int m = (node < N_NODES) ? mask[node] : 0;
  sd[threadIdx.x] = m;
  __syncthreads();
  for (int off = 1; off < 256; off <<= 1) {
    int y = (threadIdx.x >= off) ? sd[threadIdx.x - off] : 0;
    __syncthreads();
    sd[threadIdx.x] += y;
    __syncthreads();
  }
  if (threadIdx.x == 255) sbase = atomicAdd(Mcount, sd[255]);
  __syncthreads();
  if (m) list[sbase + sd[threadIdx.x] - 1] = node;
}

// ---------------- edv: pre-gather per-edge-slot dinv, list-driven ----------------

__global__ __launch_bounds__(256) void k_edv(const int* __restrict__ list,
                                             const int* __restrict__ Mcount,
                                             const unsigned short* __restrict__ esrc,
                                             const int* __restrict__ cnt,
                                             const float* __restrict__ dv,
                                             float* __restrict__ edv) {
  int j = blockIdx.x * 32 + (threadIdx.x >> 3);
  if (j >= *Mcount) return;
  int node = list[j];
  int s0 = (threadIdx.x & 7) * 8;                 // this lane's 8 slots
  int padded = min((cnt[node] + 7) & ~7, CAP);
  if (s0 >= padded) return;                       // garbage slots never read downstream
  const unsigned short* eb = esrc + (size_t)node * CAP + s0;
  ushort4 a = *(const ushort4*)(eb);
  ushort4 b = *(const ushort4*)(eb + 4);
  float4 da, db;
  da.x = dv[min((int)a.x, ZROW)]; da.y = dv[min((int)a.y, ZROW)];
  da.z = dv[min((int)a.z, ZROW)]; da.w = dv[min((int)a.w, ZROW)];
  db.x = dv[min((int)b.x, ZROW)]; db.y = dv[min((int)b.y, ZROW)];
  db.z = dv[min((int)b.z, ZROW)]; db.w = dv[min((int)b.w, ZROW)];
  *(float4*)(edv + (size_t)node * CAP + s0)     = da;
  *(float4*)(edv + (size_t)node * CAP + s0 + 4) = db;
}

// ---------------- fused agg1 + gemm2: LIST-DRIVEN, 16 nodes/block; 32 lanes/node
//                  (16 per slab plane); each edge visited once; MFMA @ W2 from LDS ----------------

__global__ __launch_bounds__(256) void k_agg_gemm2(const unsigned short* __restrict__ hs,
                                                   const int* __restrict__ cnt,
                                                   const float* __restrict__ dv,
                                                   const unsigned short* __restrict__ esrc,
                                                   const float* __restrict__ edv,
                                                   const float* __restrict__ bias,
                                                   const unsigned short* __restrict__ Wth,
                                                   const unsigned short* __restrict__ Wtl,
                                                   const int* __restrict__ list,
                                                   const int* __restrict__ Mcount,
                                                   unsigned short* __restrict__ out) {
  __shared__ __align__(16) unsigned short Ah[16 * APAD];
  __shared__ __align__(16) unsigned short Al[16 * APAD];
  __shared__ int nodeIds[16];
  int Mn = *Mcount;
  int base = blockIdx.x * 16;
  if (base >= Mn) return;
  if (threadIdx.x < 16) {
    int j = base + threadIdx.x;
    nodeIds[threadIdx.x] = (j < Mn) ? list[j] : ZROW;
  }
  __syncthreads();

  int warp = threadIdx.x >> 5, lane32 = threadIdx.x & 31;
  int half = lane32 >> 4, lane16 = lane32 & 15;   // half selects slab plane
  const ushort4* h4 = (const ushort4*)(hs + (size_t)half * PSTR);   // 16 ushort4 per row-slab

  #pragma unroll
  for (int i = 0; i < 2; ++i) {
    int row = warp * 2 + i;
    int node = nodeIds[row];
    if (node == ZROW) {                           // boundary pad: keep LDS defined, skip work
      ushort4 z = {0, 0, 0, 0};
      *(ushort4*)(&Ah[row * APAD + lane32 * 4]) = z;
      *(ushort4*)(&Al[row * APAD + lane32 * 4]) = z;
      continue;
    }
    int deg = cnt[node];
    int end = min((deg + 7) & ~7, CAP);           // padded multiple of 8
    float di = dv[node];
    ushort4 hv = h4[(size_t)node * 16 + lane16];
    float ax = di * bf2f(hv.x), ay = di * bf2f(hv.y), az = di * bf2f(hv.z), aw = di * bf2f(hv.w);
    float bx = 0.f, by = 0.f, bz = 0.f, bw = 0.f;
    const unsigned short* eb = esrc + (size_t)node * CAP;
    const float* ev = edv + (size_t)node * CAP;
    for (int e = 0; e < end; e += 8) {
      ushort4 iA = *(const ushort4*)(eb + e);     // broadcast within 32-lane group
      ushort4 iB = *(const ushort4*)(eb + e + 4);
      float4 dA = *(const float4*)(ev + e);       // sequential, broadcast within group
      float4 dB = *(const float4*)(ev + e + 4);
      ushort4 v0 = h4[(size_t)iA.x * 16 + lane16];
      ushort4 v1 = h4[(size_t)iA.y * 16 + lane16];
      ushort4 v2 = h4[(size_t)iA.z * 16 + lane16];
      ushort4 v3 = h4[(size_t)iA.w * 16 + lane16];
      ushort4 v4 = h4[(size_t)iB.x * 16 + lane16];
      ushort4 v5 = h4[(size_t)iB.y * 16 + lane16];
      ushort4 v6 = h4[(size_t)iB.z * 16 + lane16];
      ushort4 v7 = h4[(size_t)iB.w * 16 + lane16];
      ax = fmaf(dA.x, bf2f(v0.x), ax); ay = fmaf(dA.x, bf2f(v0.y), ay); az = fmaf(dA.x, bf2f(v0.z), az); aw = fmaf(dA.x, bf2f(v0.w), aw);
      bx = fmaf(dA.y, bf2f(v1.x), bx); by = fmaf(dA.y, bf2f(v1.y), by); bz = fmaf(dA.y, bf2f(v1.z), bz); bw = fmaf(dA.y, bf2f(v1.w), bw);
      ax = fmaf(dA.z, bf2f(v2.x), ax); ay = fmaf(dA.z, bf2f(v2.y), ay); az = fmaf(dA.z, bf2f(v2.z), az); aw = fmaf(dA.z, bf2f(v2.w), aw);
      bx = fmaf(dA.w, bf2f(v3.x), bx); by = fmaf(dA.w, bf2f(v3.y), by); bz = fmaf(dA.w, bf2f(v3.z), bz); bw = fmaf(dA.w, bf2f(v3.w), bw);
      ax = fmaf(dB.x, bf2f(v4.x), ax); ay = fmaf(dB.x, bf2f(v4.y), ay); az = fmaf(dB.x, bf2f(v4.z), az); aw = fmaf(dB.x, bf2f(v4.w), aw);
      bx = fmaf(dB.y, bf2f(v5.x), bx); by = fmaf(dB.y, bf2f(v5.y), by); bz = fmaf(dB.y, bf2f(v5.z), bz); bw = fmaf(dB.y, bf2f(v5.w), bw);
      ax = fmaf(dB.z, bf2f(v6.x), ax); ay = fmaf(dB.z, bf2f(v6.y), ay); az = fmaf(dB.z, bf2f(v6.z), az); aw = fmaf(dB.z, bf2f(v6.w), aw);
      bx = fmaf(dB.w, bf2f(v7.x), bx); by = fmaf(dB.w, bf2f(v7.y), by); bz = fmaf(dB.w, bf2f(v7.z), bz); bw = fmaf(dB.w, bf2f(v7.w), bw);
    }
    ax += bx; ay += by; az += bz; aw += bw;
    float4 bb = ((const float4*)bias)[lane32];    // dims lane32*4..+3 = half*64 + lane16*4
    float vx = fmaf(di, ax, bb.x), vy = fmaf(di, ay, bb.y);
    float vz = fmaf(di, az, bb.z), vw = fmaf(di, aw, bb.w);
    ushort4 hi4, lo4;
    hi4.x = f2bf(vx); lo4.x = f2bf(vx - bf2f(hi4.x));
    hi4.y = f2bf(vy); lo4.y = f2bf(vy - bf2f(hi4.y));
    hi4.z = f2bf(vz); lo4.z = f2bf(vz - bf2f(hi4.z));
    hi4.w = f2bf(vw); lo4.w = f2bf(vw - bf2f(hi4.w));
    *(ushort4*)(&Ah[row * APAD + lane32 * 4]) = hi4;
    *(ushort4*)(&Al[row * APAD + lane32 * 4]) = lo4;
  }
  __syncthreads();

  // GEMM phase: 4 wave64s, each computes rows 0..15 x cols [wave*32, wave*32+32)
  int wave = threadIdx.x >> 6, l = threadIdx.x & 63;
  int l15 = l & 15, quad = l >> 4;
  union U { uint4 u; bf16x8 h; };
  f32x4 acc[2];
  #pragma unroll
  for (int nt = 0; nt < 2; ++nt) acc[nt] = f32x4{0.f, 0.f, 0.f, 0.f};
  #pragma unroll
  for (int ks = 0; ks < 4; ++ks) {
    int k0 = ks * 32 + quad * 8;
    U ah, al;
    ah.u = *(const uint4*)(&Ah[l15 * APAD + k0]);
    al.u = *(const uint4*)(&Al[l15 * APAD + k0]);
    #pragma unroll
    for (int nt = 0; nt < 2; ++nt) {
      int n0 = wave * 32 + nt * 16;
      U bh, bl;
      bh.u = *(const uint4*)(Wth + (n0 + l15) * DIM + k0);
      bl.u = *(const uint4*)(Wtl + (n0 + l15) * DIM + k0);
      acc[nt] = __builtin_amdgcn_mfma_f32_16x16x32_bf16(ah.h, bh.h, acc[nt], 0, 0, 0);
      acc[nt] = __builtin_amdgcn_mfma_f32_16x16x32_bf16(al.h, bh.h, acc[nt], 0, 0, 0);
      acc[nt] = __builtin_amdgcn_mfma_f32_16x16x32_bf16(ah.h, bl.h, acc[nt], 0, 0, 0);
    }
  }
  #pragma unroll
  for (int reg = 0; reg < 4; ++reg) {
    int node = nodeIds[quad * 4 + reg];
    if (node != ZROW) {                           // keep hbuf2[ZROW] zeroed for pads
      #pragma unroll
      for (int nt = 0; nt < 2; ++nt)
        out[(size_t)node * DIM + wave * 32 + nt * 16 + l15] = f2bf(acc[nt][reg]);
    }
  }
}

// ---------------- full-row aggregation core (agg_batch; hbuf2 row-major, sequential edv) ----------------

static __device__ __forceinline__ float4 agg_compute(const unsigned short* __restrict__ h,
                                                     const int* __restrict__ cnt,
                                                     const float* __restrict__ dv,
                                                     const unsigned short* __restrict__ esrc,
                                                     const float* __restrict__ edv,
                                                     const float* __restrict__ bias,
                                                     int node, int lane) {
  const ushort4* h4 = (const ushort4*)h;
  int deg = cnt[node];
  int end = min((deg + 7) & ~7, CAP);              // padded length, multiple of 8
  float di = dv[node];
  ushort4 hv = h4[(size_t)node * 32 + lane];
  float ax = di * bf2f(hv.x), ay = di * bf2f(hv.y), az = di * bf2f(hv.z), aw = di * bf2f(hv.w);
  float bx = 0.f, by = 0.f, bz = 0.f, bw = 0.f;
  const unsigned short* eb = esrc + (size_t)node * CAP;
  const float* ev = edv + (size_t)node * CAP;
  for (int e = 0; e < end; e += 8) {
    ushort4 iA = *(const ushort4*)(eb + e);
    ushort4 iB = *(const ushort4*)(eb + e + 4);
    float4 dA = *(const float4*)(ev + e);
    float4 dB = *(const float4*)(ev + e + 4);
    ushort4 v0 = h4[(size_t)iA.x * 32 + lane];
    ushort4 v1 = h4[(size_t)iA.y * 32 + lane];
    ushort4 v2 = h4[(size_t)iA.z * 32 + lane];
    ushort4 v3 = h4[(size_t)iA.w * 32 + lane];
    ushort4 v4 = h4[(size_t)iB.x * 32 + lane];
    ushort4 v5 = h4[(size_t)iB.y * 32 + lane];
    ushort4 v6 = h4[(size_t)iB.z * 32 + lane];
    ushort4 v7 = h4[(size_t)iB.w * 32 + lane];
    ax = fmaf(dA.x, bf2f(v0.x), ax); ay = fmaf(dA.x, bf2f(v0.y), ay); az = fmaf(dA.x, bf2f(v0.z), az); aw = fmaf(dA.x, bf2f(v0.w), aw);
    bx = fmaf(dA.y, bf2f(v1.x), bx); by = fmaf(dA.y, bf2f(v1.y), by); bz = fmaf(dA.y, bf2f(v1.z), bz); bw = fmaf(dA.y, bf2f(v1.w), bw);
    ax = fmaf(dA.z, bf2f(v2.x), ax); ay = fmaf(dA.z, bf2f(v2.y), ay); az = fmaf(dA.z, bf2f(v2.z), az); aw = fmaf(dA.z, bf2f(v2.w), aw);
    bx = fmaf(dA.w, bf2f(v3.x), bx); by = fmaf(dA.w, bf2f(v3.y), by); bz = fmaf(dA.w, bf2f(v3.z), bz); bw = fmaf(dA.w, bf2f(v3.w), bw);
    ax = fmaf(dB.x, bf2f(v4.x), ax); ay = fmaf(dB.x, bf2f(v4.y), ay); az = fmaf(dB.x, bf2f(v4.z), az); aw = fmaf(dB.x, bf2f(v4.w), aw);
    bx = fmaf(dB.y, bf2f(v5.x), bx); by = fmaf(dB.y, bf2f(v5.y), by); bz = fmaf(dB.y, bf2f(v5.z), bz); bw = fmaf(dB.y, bf2f(v5.w), bw);
    ax = fmaf(dB.z, bf2f(v6.x), ax); ay = fmaf(dB.z, bf2f(v6.y), ay); az = fmaf(dB.z, bf2f(v6.z), az); aw = fmaf(dB.z, bf2f(v6.w), aw);
    bx = fmaf(dB.w, bf2f(v7.x), bx); by = fmaf(dB.w, bf2f(v7.y), by); bz = fmaf(dB.w, bf2f(v7.z), bz); bw = fmaf(dB.w, bf2f(v7.w), bw);
  }
  ax += bx; ay += by; az += bz; aw += bw;
  float4 bb = ((const float4*)bias)[lane];
  float4 v;
  v.x = fmaf(di, ax, bb.x); v.y = fmaf(di, ay, bb.y);
  v.z = fmaf(di, az, bb.z); v.w = fmaf(di, aw, bb.w);
  return v;
}

// ---------------- agg2 at batch positions only ----------------
// head rows -> fp32 plane pf[BATCH][128]; tail rows -> bf16 hi plane pth[BATCH][128]

__global__ __launch_bounds__(256) void k_agg_batch(const unsigned short* __restrict__ h,
                                                   const int* __restrict__ cnt,
                                                   const float* __restrict__ dv,
                                                   const unsigned short* __restrict__ esrc,
                                                   const float* __restrict__ edv,
                                                   const float* __restrict__ bias,
                                                   const int* __restrict__ head,
                                                   const int* __restrict__ tail,
                                                   float* __restrict__ pf,
                                                   unsigned short* __restrict__ pth) {
  int pos = blockIdx.x * 8 + (threadIdx.x >> 5);
  if (pos >= 2 * BATCH) return;
  int lane = threadIdx.x & 31;
  int node = (pos < BATCH) ? head[pos] : tail[pos - BATCH];
  float4 v = agg_compute(h, cnt, dv, esrc, edv, bias, node, lane);
  if (pos < BATCH) {
    ((float4*)pf)[(size_t)pos * 32 + lane] = v;
  } else {
    ushort4 hi4 = { f2bf(v.x), f2bf(v.y), f2bf(v.z), f2bf(v.w) };
    ((ushort4*)pth)[(size_t)(pos - BATCH) * 32 + lane] = hi4;
  }
}

// ---------------- predict via MFMA: tail (bf16) @ Q_r, dot with head (fp32) ----------------

__global__ __launch_bounds__(256) void k_predict_mfma(const float* __restrict__ pf,
                                                      const unsigned short* __restrict__ pth,
                                                      const unsigned short* __restrict__ Qbf,
                                                      float* __restrict__ out) {
  __shared__ __align__(16) unsigned short Qs[DIM * QPAD];
  int r = blockIdx.y;
  const unsigned short* Qr = Qbf + (size_t)r * DIM * DIM;
  for (int i = threadIdx.x; i < DIM * DIM / 8; i += 256) {
    int d = i >> 4, c = (i & 15) * 8;
    uint4 v = ((const uint4*)Qr)[i];
    *(uint4*)(&Qs[d * QPAD + c]) = v;
  }
  __syncthreads();
  int wave = threadIdx.x >> 6, lane = threadIdx.x & 63;
  int l15 = lane & 15, quad = lane >> 4;
  int bbase = blockIdx.x * 128 + wave * 32;
  int t0 = bbase + l15;                    // tail plane rows (coalesced, no gather)
  int t1 = bbase + 16 + l15;

  f32x4 acc[2][8];
  #pragma unroll
  for (int m = 0; m < 2; ++m)
    #pragma unroll
    for (int n = 0; n < 8; ++n) acc[m][n] = f32x4{0.f, 0.f, 0.f, 0.f};

  union U { uint4 u; bf16x8 h; };
  #pragma unroll
  for (int ks = 0; ks < 4; ++ks) {
    int eoff = ks * 32 + quad * 8;
    U a0, a1;
    a0.u = *(const uint4*)(pth + (size_t)t0 * DIM + eoff);
    a1.u = *(const uint4*)(pth + (size_t)t1 * DIM + eoff);
    #pragma unroll
    for (int nt = 0; nt < 8; ++nt) {
      U b; b.u = *(const uint4*)(&Qs[(nt * 16 + l15) * QPAD + eoff]);
      acc[0][nt] = __builtin_amdgcn_mfma_f32_16x16x32_bf16(a0.h, b.h, acc[0][nt], 0, 0, 0);
      acc[1][nt] = __builtin_amdgcn_mfma_f32_16x16x32_bf16(a1.h, b.h, acc[1][nt], 0, 0, 0);
    }
  }

  #pragma unroll
  for (int m = 0; m < 2; ++m) {
    #pragma unroll
    for (int reg = 0; reg < 4; ++reg) {
      int bl = bbase + m * 16 + quad * 4 + reg;             // batch index == head plane row
      float s = 0.f;
      #pragma unroll
      for (int nt = 0; nt < 8; ++nt)
        s += pf[(size_t)bl * DIM + nt * 16 + l15] * acc[m][nt][reg];   // head = fp32 plane
      #pragma unroll
      for (int off = 1; off < 16; off <<= 1) s += __shfl_xor(s, off, 64);
      if (l15 == 0) out[(size_t)bl * N_REL + r] = s;
    }
  }
}

// ---------------- launch ----------------

extern "C" void kernel_launch(void* const* d_in, const int* in_sizes, int n_in,
                              void* d_out, int out_size, void* d_ws, size_t ws_size,
                              hipStream_t stream) {
  (void)in_sizes; (void)n_in; (void)out_size; (void)ws_size;
  const float* init_emb = (const float*)d_in[0];
  const float* W1  = (const float*)d_in[1];
  const float* b1  = (const float*)d_in[2];
  const float* W2  = (const float*)d_in[3];
  const float* b2  = (const float*)d_in[4];
  const float* Rel = (const float*)d_in[5];
  const float* M   = (const float*)d_in[6];
  const int* head  = (const int*)d_in[7];
  const int* tail  = (const int*)d_in[8];
  const int* src   = (const int*)d_in[9];
  const int* dst   = src + N_EDGES;
  float* out = (float*)d_out;

  char* p = (char*)d_ws;
  auto alloc = [&](size_t bytes) { char* q = p; p += (bytes + 511) & ~(size_t)511; return q; };
  unsigned int* pe2     = (unsigned int*)alloc((size_t)NP * EB * BCAP * 4);    // 8.6 MB sub-buckets
  unsigned int* pcntBlk = (unsigned int*)alloc((size_t)EB * NP * 4);           // per-(block,bin) counts
  int*   cnt  = (int*)alloc((size_t)N_NODES * 4);
  float* dv   = (float*)alloc((size_t)(N_NODES + 1) * 4);                      // +1 sentinel
  int*   mask = (int*)alloc((size_t)(N_NODES + 1) * 4);                        // needed-node mask
  int*   list = (int*)alloc((size_t)N_NODES * 4);                              // compacted needed nodes
  int*   Mcount = (int*)alloc(64);
  unsigned short* esrc = (unsigned short*)alloc((size_t)N_NODES * CAP * 2);    // 6.4 MB u16 buckets
  float* edv = (float*)alloc((size_t)N_NODES * CAP * 4);                       // 12.8 MB per-slot dinv
  unsigned short* hs    = (unsigned short*)alloc((size_t)NSLAB * PSTR * 2);    // slab-major h1 (+zero row)
  unsigned short* hbuf2 = (unsigned short*)alloc((size_t)(N_NODES + 1) * DIM * 2);  // +1 zero row
  float*          pf    = (float*)alloc((size_t)BATCH * DIM * 4);              // head plane fp32
  unsigned short* pth   = (unsigned short*)alloc((size_t)BATCH * DIM * 2);     // tail plane bf16 hi
  unsigned short* Qbf   = (unsigned short*)alloc((size_t)N_REL * DIM * DIM * 2);
  unsigned short* W1th  = (unsigned short*)alloc((size_t)DIM * DIM * 2);
  unsigned short* W1tl  = (unsigned short*)alloc((size_t)DIM * DIM * 2);
  unsigned short* W2th  = (unsigned short*)alloc((size_t)DIM * DIM * 2);
  unsigned short* W2tl  = (unsigned short*)alloc((size_t)DIM * DIM * 2);
  unsigned short* Mth   = (unsigned short*)alloc((size_t)DIM * DIM * 2);

  // 0: weight prep + sentinel zeroing + mask/Mcount zero
  k_prep<<<DIM * DIM / 256, 256, 0, stream>>>(W1, W2, M, W1th, W1tl, W2th, W2tl, Mth,
                                              hs, hbuf2, dv, mask, Mcount);
  // 1: one-pass edge scatter (fixed sub-buckets) || decoder TQ || gemm1
  k_mega1<<<EB + G_TQ + G_GEMM, 256, 0, stream>>>(src, dst, pe2, pcntBlk, Rel, Mth, Qbf,
                                                  init_emb, W1th, W1tl, hs);
  // 2: ragged per-partition bucket fill (u16, pad-to-8) -> esrc + cnt + dinv
  k_build<<<NP, 256, 0, stream>>>(pe2, pcntBlk, esrc, cnt, dv);
  // 3: mark needed set (batch nodes + neighbors)
  k_mark<<<(2 * BATCH + 7) / 8, 256, 0, stream>>>(head, tail, esrc, cnt, mask);
  // 4: compact mask -> list (Mcount)
  k_compact<<<(N_NODES + 255) / 256, 256, 0, stream>>>(mask, list, Mcount);
  // 5: pre-gather per-slot dinv -> edv (list-driven)
  k_edv<<<(N_NODES + 31) / 32, 256, 0, stream>>>(list, Mcount, esrc, cnt, dv, edv);
  // 6: fused agg1 + gemm2 (list-driven; both slab planes; MFMA from LDS)
  k_agg_gemm2<<<(N_NODES + 15) / 16, 256, 0, stream>>>(hs, cnt, dv, esrc, edv, b1, W2th, W2tl,
                                                       list, Mcount, hbuf2);
  // 7: agg2 only at batch positions -> compact planes (head fp32, tail bf16)
  k_agg_batch<<<(2 * BATCH + 7) / 8, 256, 0, stream>>>(hbuf2, cnt, dv, esrc, edv, b2, head, tail, pf, pth);
  // 8: predict (coalesced reads from compact planes)
  k_predict_mfma<<<dim3(BATCH / 128, N_REL), 256, 0, stream>>>(pf, pth, Qbf, out);
}

// Round 12
// 214.107 us; speedup vs baseline: 1.0349x; 1.0349x over previous
//
#include <hip/hip_runtime.h>

#define N_NODES 50000
#define N_EDGES 800000
#define DIM 128
#define N_REL 86
#define BATCH 2048
#define CAP 64               // per-node bucket capacity; max deg ~45 for Poisson(16)
#define ZROW N_NODES         // sentinel row: zeroed embedding row, dv[ZROW]=0 (fits u16)

#define NP 196               // partitions by dst>>8 (256 nodes each; ceil(50000/256))
#define EB 196               // edge blocks for build (4096 edges each)
#define PCAP 8192            // partition edge capacity (mean 4096, sigma 64)

#define NSLAB 2              // 64-dim slabs; slab-major planes, 6.4 MB each
#define PSTR ((size_t)(N_NODES + 1) * 64)                       // ushorts per slab plane

using bf16x8 = __attribute__((ext_vector_type(8))) short;
using f32x4  = __attribute__((ext_vector_type(4))) float;

// float -> bf16 round-to-nearest-even (finite inputs)
static __device__ __forceinline__ unsigned short f2bf(float f) {
  union { float f; unsigned int i; } v; v.f = f;
  unsigned int x = v.i;
  unsigned int r = x + 0x7FFFu + ((x >> 16) & 1u);
  return (unsigned short)(r >> 16);
}
static __device__ __forceinline__ float bf2f(unsigned short u) {
  union { unsigned int i; float f; } v;
  v.i = ((unsigned int)u) << 16;
  return v.f;
}

#define G_TQ    172           // 86 relations x 2 d-blocks
#define G_GEMM  391           // ceil(50000/128)
#define TPAD 136              // 128+8 bf16: 272 B row stride -> 2-way bank alias (free)
#define QPAD 136
#define APAD 136

// ---------------- kernel 0: weight prep + sentinel zeroing + pcnt/mask/Mcount zero ----------------

__global__ __launch_bounds__(256) void k_prep(const float* __restrict__ W1, const float* __restrict__ W2,
                                              const float* __restrict__ M,
                                              unsigned short* __restrict__ W1th, unsigned short* __restrict__ W1tl,
                                              unsigned short* __restrict__ W2th, unsigned short* __restrict__ W2tl,
                                              unsigned short* __restrict__ Mth,
                                              unsigned short* __restrict__ hs,
                                              unsigned short* __restrict__ hbuf2,
                                              float* __restrict__ dv,
                                              unsigned int* __restrict__ pcnt,
                                              int* __restrict__ mask,
                                              int* __restrict__ Mcount) {
  int g = blockIdx.x * 256 + threadIdx.x;          // 16384 threads = DIM*DIM
  if (g < NP) pcnt[g] = 0u;                        // partition atomic counters
  #pragma unroll
  for (int q = 0; q < 4; ++q) {                    // zero needed-mask (N+1 entries)
    int idx = g + q * 16384;
    if (idx <= N_NODES) mask[idx] = 0;
  }
  // zero sentinel rows (gather pads resolve to ZROW; must be 0.0 not garbage/NaN)
  if (g < 32) {                                    // 2 slab planes x 16 ushort4
    ushort4 z = {0, 0, 0, 0};
    ((ushort4*)(hs + (size_t)(g >> 4) * PSTR))[(size_t)ZROW * 16 + (g & 15)] = z;
  }
  if (g >= 32 && g < 64) {                         // hbuf2 row (32 ushort4)
    ushort4 z = {0, 0, 0, 0};
    ((ushort4*)hbuf2)[(size_t)ZROW * 32 + (g - 32)] = z;
  }
  if (g == 64) dv[ZROW] = 0.f;
  if (g == 65) *Mcount = 0;
  int k = g >> 7, n = g & 127;
  int t = n * DIM + k;
  float w1 = W1[g];
  unsigned short h1 = f2bf(w1);
  W1th[t] = h1;
  W1tl[t] = f2bf(w1 - bf2f(h1));
  float w2 = W2[g];
  unsigned short h2 = f2bf(w2);
  W2th[t] = h2;
  W2tl[t] = f2bf(w2 - bf2f(h2));
  Mth[t] = f2bf(M[g]);
}

// ---------------- mega1: edge build (regs held across hist -> reserve -> scatter)
//                         ||  decoder TQ  ||  gemm1 (slab-major out) ----------------
// pe entry: (dst & 255) << 17 | src     (src < 50000 < 2^17)

__global__ __launch_bounds__(256) void k_mega1(const int* __restrict__ src, const int* __restrict__ dst,
                                               unsigned int* __restrict__ pcnt,
                                               unsigned int* __restrict__ pe,
                                               const float* __restrict__ Rel,
                                               const unsigned short* __restrict__ Mth,
                                               unsigned short* __restrict__ Qbf,
                                               const float* __restrict__ x,
                                               const unsigned short* __restrict__ W1th,
                                               const unsigned short* __restrict__ W1tl,
                                               unsigned short* __restrict__ hs) {
  __shared__ __align__(16) unsigned char smem[64 * TPAD * 2];   // max(hist 784B, Ts 17408B)
  int bid = blockIdx.x;
  union U { uint4 u; bf16x8 h; };

  if (bid < EB) {
    unsigned int* hist = (unsigned int*)smem;
    int t = threadIdx.x;
    if (t < NP) hist[t] = 0u;
    __syncthreads();
    // ---- load edges ONCE into registers, histogram ----
    int4 sA[4], dA[4];
    #pragma unroll
    for (int j = 0; j < 4; ++j) {
      int i0 = bid * 4096 + j * 1024 + t * 4;
      if (i0 < N_EDGES) {
        sA[j] = *(const int4*)(src + i0);
        dA[j] = *(const int4*)(dst + i0);
        atomicAdd(&hist[dA[j].x >> 8], 1u);
        atomicAdd(&hist[dA[j].y >> 8], 1u);
        atomicAdd(&hist[dA[j].z >> 8], 1u);
        atomicAdd(&hist[dA[j].w >> 8], 1u);
      }
    }
    __syncthreads();
    // ---- reserve global ranges: one atomic per (block, bin) ----
    if (t < NP) {
      unsigned int c = hist[t];
      unsigned int base = c ? atomicAdd(&pcnt[t], c) : 0u;
      hist[t] = (unsigned int)t * PCAP + base;     // becomes this block's write cursor
    }
    __syncthreads();
    // ---- scatter from registers via LDS cursor ----
    #pragma unroll
    for (int j = 0; j < 4; ++j) {
      int i0 = bid * 4096 + j * 1024 + t * 4;
      if (i0 < N_EDGES) {
        int b0 = dA[j].x >> 8, b1 = dA[j].y >> 8, b2 = dA[j].z >> 8, b3 = dA[j].w >> 8;
        unsigned int p0 = atomicAdd(&hist[b0], 1u);
        unsigned int p1 = atomicAdd(&hist[b1], 1u);
        unsigned int p2 = atomicAdd(&hist[b2], 1u);
        unsigned int p3 = atomicAdd(&hist[b3], 1u);
        if (p0 < (unsigned int)(b0 + 1) * PCAP) pe[p0] = ((unsigned)(dA[j].x & 255) << 17) | (unsigned)sA[j].x;
        if (p1 < (unsigned int)(b1 + 1) * PCAP) pe[p1] = ((unsigned)(dA[j].y & 255) << 17) | (unsigned)sA[j].y;
        if (p2 < (unsigned int)(b2 + 1) * PCAP) pe[p2] = ((unsigned)(dA[j].z & 255) << 17) | (unsigned)sA[j].z;
        if (p3 < (unsigned int)(b3 + 1) * PCAP) pe[p3] = ((unsigned)(dA[j].w & 255) << 17) | (unsigned)sA[j].w;
      }
    }
    return;
  }

  int wave = threadIdx.x >> 6, lane = threadIdx.x & 63;
  int l15 = lane & 15, quad = lane >> 4;

  if (bid < EB + G_TQ) {
    // ---- decoder precompute: T_r = Rel_r @ M (LDS), Q_r = T_r @ Rel_r^T ----
    unsigned short* Ts = (unsigned short*)smem;
    int tb = bid - EB;                       // [0, 172)
    int r = tb >> 1, dblk = tb & 1;
    const float* Rr = Rel + (size_t)r * DIM * DIM;
    unsigned short* Qr = Qbf + (size_t)r * DIM * DIM;
    int dw = dblk * 64 + wave * 16;
    f32x4 acc[8];
    #pragma unroll
    for (int nt = 0; nt < 8; ++nt) acc[nt] = f32x4{0.f, 0.f, 0.f, 0.f};
    #pragma unroll
    for (int ks = 0; ks < 4; ++ks) {
      int k0 = ks * 32 + quad * 8;
      const float* ap = Rr + (size_t)(dw + l15) * DIM + k0;
      float av[8];
      *(float4*)(av)     = *(const float4*)(ap);
      *(float4*)(av + 4) = *(const float4*)(ap + 4);
      bf16x8 a;
      #pragma unroll
      for (int j = 0; j < 8; ++j) a[j] = (short)f2bf(av[j]);
      #pragma unroll
      for (int nt = 0; nt < 8; ++nt) {
        U b; b.u = *(const uint4*)(Mth + (nt * 16 + l15) * DIM + k0);
        acc[nt] = __builtin_amdgcn_mfma_f32_16x16x32_bf16(a, b.h, acc[nt], 0, 0, 0);
      }
    }
    #pragma unroll
    for (int nt = 0; nt < 8; ++nt)
      #pragma unroll
      for (int reg = 0; reg < 4; ++reg)
        Ts[(wave * 16 + quad * 4 + reg) * TPAD + nt * 16 + l15] = f2bf(acc[nt][reg]);
    __syncthreads();
    f32x4 qacc[8];
    #pragma unroll
    for (int nt = 0; nt < 8; ++nt) qacc[nt] = f32x4{0.f, 0.f, 0.f, 0.f};
    #pragma unroll
    for (int ks = 0; ks < 4; ++ks) {
      int k0 = ks * 32 + quad * 8;
      U a; a.u = *(const uint4*)(Ts + (wave * 16 + l15) * TPAD + k0);
      #pragma unroll
      for (int nt = 0; nt < 8; ++nt) {
        const float* bp = Rr + (size_t)(nt * 16 + l15) * DIM + k0;
        float bv[8];
        *(float4*)(bv)     = *(const float4*)(bp);
        *(float4*)(bv + 4) = *(const float4*)(bp + 4);
        bf16x8 b;
        #pragma unroll
        for (int j = 0; j < 8; ++j) b[j] = (short)f2bf(bv[j]);
        qacc[nt] = __builtin_amdgcn_mfma_f32_16x16x32_bf16(a.h, b, qacc[nt], 0, 0, 0);
      }
    }
    #pragma unroll
    for (int nt = 0; nt < 8; ++nt)
      #pragma unroll
      for (int reg = 0; reg < 4; ++reg)
        Qr[(size_t)(dw + quad * 4 + reg) * DIM + nt * 16 + l15] = f2bf(qacc[nt][reg]);
    return;
  }

  // ---- node GEMM layer 1: hs = slab-major(x @ W1) (hi/lo 3-term, bf16 out) ----
  int r0 = (bid - EB - G_TQ) * 128 + wave * 32;
  f32x4 acc[2][8];
  #pragma unroll
  for (int mt = 0; mt < 2; ++mt)
    #pragma unroll
    for (int nt = 0; nt < 8; ++nt) acc[mt][nt] = f32x4{0.f, 0.f, 0.f, 0.f};
  #pragma unroll
  for (int ks = 0; ks < 4; ++ks) {
    int k0 = ks * 32 + quad * 8;
    bf16x8 ah[2], al[2];
    #pragma unroll
    for (int mt = 0; mt < 2; ++mt) {
      int row = r0 + mt * 16 + l15;
      row = (row < N_NODES) ? row : (N_NODES - 1);
      const float* xp = x + (size_t)row * DIM + k0;
      float xv[8];
      *(float4*)(xv)     = *(const float4*)(xp);
      *(float4*)(xv + 4) = *(const float4*)(xp + 4);
      #pragma unroll
      for (int j = 0; j < 8; ++j) {
        unsigned short h = f2bf(xv[j]);
        ah[mt][j] = (short)h;
        al[mt][j] = (short)f2bf(xv[j] - bf2f(h));
      }
    }
    #pragma unroll
    for (int nt = 0; nt < 8; ++nt) {
      U bh, bl;
      bh.u = *(const uint4*)(W1th + (nt * 16 + l15) * DIM + k0);
      bl.u = *(const uint4*)(W1tl + (nt * 16 + l15) * DIM + k0);
      #pragma unroll
      for (int mt = 0; mt < 2; ++mt) {
        acc[mt][nt] = __builtin_amdgcn_mfma_f32_16x16x32_bf16(ah[mt], bh.h, acc[mt][nt], 0, 0, 0);
        acc[mt][nt] = __builtin_amdgcn_mfma_f32_16x16x32_bf16(al[mt], bh.h, acc[mt][nt], 0, 0, 0);
        acc[mt][nt] = __builtin_amdgcn_mfma_f32_16x16x32_bf16(ah[mt], bl.h, acc[mt][nt], 0, 0, 0);
      }
    }
  }
  #pragma unroll
  for (int mt = 0; mt < 2; ++mt)
    #pragma unroll
    for (int reg = 0; reg < 4; ++reg) {
      int row = r0 + mt * 16 + quad * 4 + reg;
      if (row < N_NODES) {
        #pragma unroll
        for (int nt = 0; nt < 8; ++nt)
          hs[(size_t)(nt >> 2) * PSTR + (size_t)row * 64 + (nt & 3) * 16 + l15] = f2bf(acc[mt][nt][reg]);
      }
    }
}

// ---------------- build: per-partition bucket fill (u16) + pad-to-8 + cnt + dinv ----------------

__global__ __launch_bounds__(256) void k_build(const unsigned int* __restrict__ pe,
                                               const unsigned int* __restrict__ partCnt,
                                               unsigned short* __restrict__ esrc, int* __restrict__ cnt,
                                               float* __restrict__ dv) {
  __shared__ unsigned int c256[256];
  int p = blockIdx.x, t = threadIdx.x;
  c256[t] = 0u;
  __syncthreads();
  int m = min((int)partCnt[p], PCAP);
  for (int i = t; i < m; i += 256) {
    unsigned int e = pe[(size_t)p * PCAP + i];
    unsigned int local = e >> 17;
    unsigned int s = e & 0x1FFFFu;
    unsigned int slot = atomicAdd(&c256[local], 1u);
    int node = p * 256 + (int)local;
    if (slot < CAP) esrc[(size_t)node * CAP + slot] = (unsigned short)s;
  }
  __syncthreads();
  int node = p * 256 + t;
  if (node < N_NODES) {
    int c = (int)c256[t];
    cnt[node] = c;
    dv[node] = rsqrtf((float)(c + 1));
    int padded = min((c + 7) & ~7, CAP);          // pad bucket to multiple of 8
    for (int s = c; s < padded; ++s) esrc[(size_t)node * CAP + s] = (unsigned short)ZROW;
  }
}

// ---------------- mark: needed set = batch nodes + their neighbors ----------------

__global__ __launch_bounds__(256) void k_mark(const int* __restrict__ head, const int* __restrict__ tail,
                                              const unsigned short* __restrict__ esrc,
                                              const int* __restrict__ cnt,
                                              int* __restrict__ mask) {
  int pos = blockIdx.x * 8 + (threadIdx.x >> 5);
  if (pos >= 2 * BATCH) return;
  int lane = threadIdx.x & 31;
  int node = (pos < BATCH) ? head[pos] : tail[pos - BATCH];
  if (lane == 0) mask[node] = 1;
  int deg = min(cnt[node], CAP);
  const unsigned short* eb = esrc + (size_t)node * CAP;
  if (lane < deg) mask[eb[lane]] = 1;
  if (lane + 32 < deg) mask[eb[lane + 32]] = 1;
}

// ---------------- compact: mask -> node list (unordered across blocks) ----------------

__global__ __launch_bounds__(256) void k_compact(const int* __restrict__ mask,
                                                 int* __restrict__ list,
                                                 int* __restrict__ Mcount) {
  __shared__ int sd[256];
  __shared__ int sbase;
  int node = blockIdx.x * 256 + threadIdx.x;
  int m = (node < N_NODES) ? mask[node] : 0;
  sd[threadIdx.x] = m;
  __syncthreads();
  for (int off = 1; off < 256; off <<= 1) {
    int y = (threadIdx.x >= off) ? sd[threadIdx.x - off] : 0;
    __syncthreads();
    sd[threadIdx.x] += y;
    __syncthreads();
  }
  if (threadIdx.x == 255) sbase = atomicAdd(Mcount, sd[255]);
  __syncthreads();
  if (m) list[sbase + sd[threadIdx.x] - 1] = node;
}

// ---------------- edv: pre-gather per-edge-slot dinv, list-driven ----------------

__global__ __launch_bounds__(256) void k_edv(const int* __restrict__ list,
                                             const int* __restrict__ Mcount,
                                             const unsigned short* __restrict__ esrc,
                                             const int* __restrict__ cnt,
                                             const float* __restrict__ dv,
                                             float* __restrict__ edv) {
  int j = blockIdx.x * 32 + (threadIdx.x >> 3);
  if (j >= *Mcount) return;
  int node = list[j];
  int s0 = (threadIdx.x & 7) * 8;                 // this lane's 8 slots
  int padded = min((cnt[node] + 7) & ~7, CAP);
  if (s0 >= padded) return;                       // garbage slots never read downstream
  const unsigned short* eb = esrc + (size_t)node * CAP + s0;
  ushort4 a = *(const ushort4*)(eb);
  ushort4 b = *(const ushort4*)(eb + 4);
  float4 da, db;
  da.x = dv[min((int)a.x, ZROW)]; da.y = dv[min((int)a.y, ZROW)];
  da.z = dv[min((int)a.z, ZROW)]; da.w = dv[min((int)a.w, ZROW)];
  db.x = dv[min((int)b.x, ZROW)]; db.y = dv[min((int)b.y, ZROW)];
  db.z = dv[min((int)b.z, ZROW)]; db.w = dv[min((int)b.w, ZROW)];
  *(float4*)(edv + (size_t)node * CAP + s0)     = da;
  *(float4*)(edv + (size_t)node * CAP + s0 + 4) = db;
}

// ---------------- fused agg1 + gemm2: LIST-DRIVEN, 16 nodes/block; 32 lanes/node
//                  (16 per slab plane); each edge visited once; MFMA @ W2 from LDS ----------------

__global__ __launch_bounds__(256) void k_agg_gemm2(const unsigned short* __restrict__ hs,
                                                   const int* __restrict__ cnt,
                                                   const float* __restrict__ dv,
                                                   const unsigned short* __restrict__ esrc,
                                                   const float* __restrict__ edv,
                                                   const float* __restrict__ bias,
                                                   const unsigned short* __restrict__ Wth,
                                                   const unsigned short* __restrict__ Wtl,
                                                   const int* __restrict__ list,
                                                   const int* __restrict__ Mcount,
                                                   unsigned short* __restrict__ out) {
  __shared__ __align__(16) unsigned short Ah[16 * APAD];
  __shared__ __align__(16) unsigned short Al[16 * APAD];
  __shared__ int nodeIds[16];
  int Mn = *Mcount;
  int base = blockIdx.x * 16;
  if (base >= Mn) return;
  if (threadIdx.x < 16) {
    int j = base + threadIdx.x;
    nodeIds[threadIdx.x] = (j < Mn) ? list[j] : ZROW;
  }
  __syncthreads();

  int warp = threadIdx.x >> 5, lane32 = threadIdx.x & 31;
  int half = lane32 >> 4, lane16 = lane32 & 15;   // half selects slab plane
  const ushort4* h4 = (const ushort4*)(hs + (size_t)half * PSTR);   // 16 ushort4 per row-slab

  #pragma unroll
  for (int i = 0; i < 2; ++i) {
    int row = warp * 2 + i;
    int node = nodeIds[row];
    if (node == ZROW) {                           // boundary pad: keep LDS defined, skip work
      ushort4 z = {0, 0, 0, 0};
      *(ushort4*)(&Ah[row * APAD + lane32 * 4]) = z;
      *(ushort4*)(&Al[row * APAD + lane32 * 4]) = z;
      continue;
    }
    int deg = cnt[node];
    int end = min((deg + 7) & ~7, CAP);           // padded multiple of 8
    float di = dv[node];
    ushort4 hv = h4[(size_t)node * 16 + lane16];
    float ax = di * bf2f(hv.x), ay = di * bf2f(hv.y), az = di * bf2f(hv.z), aw = di * bf2f(hv.w);
    float bx = 0.f, by = 0.f, bz = 0.f, bw = 0.f;
    const unsigned short* eb = esrc + (size_t)node * CAP;
    const float* ev = edv + (size_t)node * CAP;
    for (int e = 0; e < end; e += 8) {
      ushort4 iA = *(const ushort4*)(eb + e);     // broadcast within 32-lane group
      ushort4 iB = *(const ushort4*)(eb + e + 4);
      float4 dA = *(const float4*)(ev + e);       // sequential, broadcast within group
      float4 dB = *(const float4*)(ev + e + 4);
      ushort4 v0 = h4[(size_t)iA.x * 16 + lane16];
      ushort4 v1 = h4[(size_t)iA.y * 16 + lane16];
      ushort4 v2 = h4[(size_t)iA.z * 16 + lane16];
      ushort4 v3 = h4[(size_t)iA.w * 16 + lane16];
      ushort4 v4 = h4[(size_t)iB.x * 16 + lane16];
      ushort4 v5 = h4[(size_t)iB.y * 16 + lane16];
      ushort4 v6 = h4[(size_t)iB.z * 16 + lane16];
      ushort4 v7 = h4[(size_t)iB.w * 16 + lane16];
      ax = fmaf(dA.x, bf2f(v0.x), ax); ay = fmaf(dA.x, bf2f(v0.y), ay); az = fmaf(dA.x, bf2f(v0.z), az); aw = fmaf(dA.x, bf2f(v0.w), aw);
      bx = fmaf(dA.y, bf2f(v1.x), bx); by = fmaf(dA.y, bf2f(v1.y), by); bz = fmaf(dA.y, bf2f(v1.z), bz); bw = fmaf(dA.y, bf2f(v1.w), bw);
      ax = fmaf(dA.z, bf2f(v2.x), ax); ay = fmaf(dA.z, bf2f(v2.y), ay); az = fmaf(dA.z, bf2f(v2.z), az); aw = fmaf(dA.z, bf2f(v2.w), aw);
      bx = fmaf(dA.w, bf2f(v3.x), bx); by = fmaf(dA.w, bf2f(v3.y), by); bz = fmaf(dA.w, bf2f(v3.z), bz); bw = fmaf(dA.w, bf2f(v3.w), bw);
      ax = fmaf(dB.x, bf2f(v4.x), ax); ay = fmaf(dB.x, bf2f(v4.y), ay); az = fmaf(dB.x, bf2f(v4.z), az); aw = fmaf(dB.x, bf2f(v4.w), aw);
      bx = fmaf(dB.y, bf2f(v5.x), bx); by = fmaf(dB.y, bf2f(v5.y), by); bz = fmaf(dB.y, bf2f(v5.z), bz); bw = fmaf(dB.y, bf2f(v5.w), bw);
      ax = fmaf(dB.z, bf2f(v6.x), ax); ay = fmaf(dB.z, bf2f(v6.y), ay); az = fmaf(dB.z, bf2f(v6.z), az); aw = fmaf(dB.z, bf2f(v6.w), aw);
      bx = fmaf(dB.w, bf2f(v7.x), bx); by = fmaf(dB.w, bf2f(v7.y), by); bz = fmaf(dB.w, bf2f(v7.z), bz); bw = fmaf(dB.w, bf2f(v7.w), bw);
    }
    ax += bx; ay += by; az += bz; aw += bw;
    float4 bb = ((const float4*)bias)[lane32];    // dims lane32*4..+3 = half*64 + lane16*4
    float vx = fmaf(di, ax, bb.x), vy = fmaf(di, ay, bb.y);
    float vz = fmaf(di, az, bb.z), vw = fmaf(di, aw, bb.w);
    ushort4 hi4, lo4;
    hi4.x = f2bf(vx); lo4.x = f2bf(vx - bf2f(hi4.x));
    hi4.y = f2bf(vy); lo4.y = f2bf(vy - bf2f(hi4.y));
    hi4.z = f2bf(vz); lo4.z = f2bf(vz - bf2f(hi4.z));
    hi4.w = f2bf(vw); lo4.w = f2bf(vw - bf2f(hi4.w));
    *(ushort4*)(&Ah[row * APAD + lane32 * 4]) = hi4;
    *(ushort4*)(&Al[row * APAD + lane32 * 4]) = lo4;
  }
  __syncthreads();

  // GEMM phase: 4 wave64s, each computes rows 0..15 x cols [wave*32, wave*32+32)
  int wave = threadIdx.x >> 6, l = threadIdx.x & 63;
  int l15 = l & 15, quad = l >> 4;
  union U { uint4 u; bf16x8 h; };
  f32x4 acc[2];
  #pragma unroll
  for (int nt = 0; nt < 2; ++nt) acc[nt] = f32x4{0.f, 0.f, 0.f, 0.f};
  #pragma unroll
  for (int ks = 0; ks < 4; ++ks) {
    int k0 = ks * 32 + quad * 8;
    U ah, al;
    ah.u = *(const uint4*)(&Ah[l15 * APAD + k0]);
    al.u = *(const uint4*)(&Al[l15 * APAD + k0]);
    #pragma unroll
    for (int nt = 0; nt < 2; ++nt) {
      int n0 = wave * 32 + nt * 16;
      U bh, bl;
      bh.u = *(const uint4*)(Wth + (n0 + l15) * DIM + k0);
      bl.u = *(const uint4*)(Wtl + (n0 + l15) * DIM + k0);
      acc[nt] = __builtin_amdgcn_mfma_f32_16x16x32_bf16(ah.h, bh.h, acc[nt], 0, 0, 0);
      acc[nt] = __builtin_amdgcn_mfma_f32_16x16x32_bf16(al.h, bh.h, acc[nt], 0, 0, 0);
      acc[nt] = __builtin_amdgcn_mfma_f32_16x16x32_bf16(ah.h, bl.h, acc[nt], 0, 0, 0);
    }
  }
  #pragma unroll
  for (int reg = 0; reg < 4; ++reg) {
    int node = nodeIds[quad * 4 + reg];
    if (node != ZROW) {                           // keep hbuf2[ZROW] zeroed for pads
      #pragma unroll
      for (int nt = 0; nt < 2; ++nt)
        out[(size_t)node * DIM + wave * 32 + nt * 16 + l15] = f2bf(acc[nt][reg]);
    }
  }
}

// ---------------- full-row aggregation core (agg_batch; hbuf2 row-major, sequential edv) ----------------

static __device__ __forceinline__ float4 agg_compute(const unsigned short* __restrict__ h,
                                                     const int* __restrict__ cnt,
                                                     const float* __restrict__ dv,
                                                     const unsigned short* __restrict__ esrc,
                                                     const float* __restrict__ edv,
                                                     const float* __restrict__ bias,
                                                     int node, int lane) {
  const ushort4* h4 = (const ushort4*)h;
  int deg = cnt[node];
  int end = min((deg + 7) & ~7, CAP);              // padded length, multiple of 8
  float di = dv[node];
  ushort4 hv = h4[(size_t)node * 32 + lane];
  float ax = di * bf2f(hv.x), ay = di * bf2f(hv.y), az = di * bf2f(hv.z), aw = di * bf2f(hv.w);
  float bx = 0.f, by = 0.f, bz = 0.f, bw = 0.f;
  const unsigned short* eb = esrc + (size_t)node * CAP;
  const float* ev = edv + (size_t)node * CAP;
  for (int e = 0; e < end; e += 8) {
    ushort4 iA = *(const ushort4*)(eb + e);
    ushort4 iB = *(const ushort4*)(eb + e + 4);
    float4 dA = *(const float4*)(ev + e);
    float4 dB = *(const float4*)(ev + e + 4);
    ushort4 v0 = h4[(size_t)iA.x * 32 + lane];
    ushort4 v1 = h4[(size_t)iA.y * 32 + lane];
    ushort4 v2 = h4[(size_t)iA.z * 32 + lane];
    ushort4 v3 = h4[(size_t)iA.w * 32 + lane];
    ushort4 v4 = h4[(size_t)iB.x * 32 + lane];
    ushort4 v5 = h4[(size_t)iB.y * 32 + lane];
    ushort4 v6 = h4[(size_t)iB.z * 32 + lane];
    ushort4 v7 = h4[(size_t)iB.w * 32 + lane];
    ax = fmaf(dA.x, bf2f(v0.x), ax); ay = fmaf(dA.x, bf2f(v0.y), ay); az = fmaf(dA.x, bf2f(v0.z), az); aw = fmaf(dA.x, bf2f(v0.w), aw);
    bx = fmaf(dA.y, bf2f(v1.x), bx); by = fmaf(dA.y, bf2f(v1.y), by); bz = fmaf(dA.y, bf2f(v1.z), bz); bw = fmaf(dA.y, bf2f(v1.w), bw);
    ax = fmaf(dA.z, bf2f(v2.x), ax); ay = fmaf(dA.z, bf2f(v2.y), ay); az = fmaf(dA.z, bf2f(v2.z), az); aw = fmaf(dA.z, bf2f(v2.w), aw);
    bx = fmaf(dA.w, bf2f(v3.x), bx); by = fmaf(dA.w, bf2f(v3.y), by); bz = fmaf(dA.w, bf2f(v3.z), bz); bw = fmaf(dA.w, bf2f(v3.w), bw);
    ax = fmaf(dB.x, bf2f(v4.x), ax); ay = fmaf(dB.x, bf2f(v4.y), ay); az = fmaf(dB.x, bf2f(v4.z), az); aw = fmaf(dB.x, bf2f(v4.w), aw);
    bx = fmaf(dB.y, bf2f(v5.x), bx); by = fmaf(dB.y, bf2f(v5.y), by); bz = fmaf(dB.y, bf2f(v5.z), bz); bw = fmaf(dB.y, bf2f(v5.w), bw);
    ax = fmaf(dB.z, bf2f(v6.x), ax); ay = fmaf(dB.z, bf2f(v6.y), ay); az = fmaf(dB.z, bf2f(v6.z), az); aw = fmaf(dB.z, bf2f(v6.w), aw);
    bx = fmaf(dB.w, bf2f(v7.x), bx); by = fmaf(dB.w, bf2f(v7.y), by); bz = fmaf(dB.w, bf2f(v7.z), bz); bw = fmaf(dB.w, bf2f(v7.w), bw);
  }
  ax += bx; ay += by; az += bz; aw += bw;
  float4 bb = ((const float4*)bias)[lane];
  float4 v;
  v.x = fmaf(di, ax, bb.x); v.y = fmaf(di, ay, bb.y);
  v.z = fmaf(di, az, bb.z); v.w = fmaf(di, aw, bb.w);
  return v;
}

// ---------------- agg2 at batch positions only ----------------
// head rows -> fp32 plane pf[BATCH][128]; tail rows -> bf16 hi plane pth[BATCH][128]

__global__ __launch_bounds__(256) void k_agg_batch(const unsigned short* __restrict__ h,
                                                   const int* __restrict__ cnt,
                                                   const float* __restrict__ dv,
                                                   const unsigned short* __restrict__ esrc,
                                                   const float* __restrict__ edv,
                                                   const float* __restrict__ bias,
                                                   const int* __restrict__ head,
                                                   const int* __restrict__ tail,
                                                   float* __restrict__ pf,
                                                   unsigned short* __restrict__ pth) {
  int pos = blockIdx.x * 8 + (threadIdx.x >> 5);
  if (pos >= 2 * BATCH) return;
  int lane = threadIdx.x & 31;
  int node = (pos < BATCH) ? head[pos] : tail[pos - BATCH];
  float4 v = agg_compute(h, cnt, dv, esrc, edv, bias, node, lane);
  if (pos < BATCH) {
    ((float4*)pf)[(size_t)pos * 32 + lane] = v;
  } else {
    ushort4 hi4 = { f2bf(v.x), f2bf(v.y), f2bf(v.z), f2bf(v.w) };
    ((ushort4*)pth)[(size_t)(pos - BATCH) * 32 + lane] = hi4;
  }
}

// ---------------- predict via MFMA: tail (bf16) @ Q_r, dot with head (fp32) ----------------

__global__ __launch_bounds__(256) void k_predict_mfma(const float* __restrict__ pf,
                                                      const unsigned short* __restrict__ pth,
                                                      const unsigned short* __restrict__ Qbf,
                                                      float* __restrict__ out) {
  __shared__ __align__(16) unsigned short Qs[DIM * QPAD];
  int r = blockIdx.y;
  const unsigned short* Qr = Qbf + (size_t)r * DIM * DIM;
  for (int i = threadIdx.x; i < DIM * DIM / 8; i += 256) {
    int d = i >> 4, c = (i & 15) * 8;
    uint4 v = ((const uint4*)Qr)[i];
    *(uint4*)(&Qs[d * QPAD + c]) = v;
  }
  __syncthreads();
  int wave = threadIdx.x >> 6, lane = threadIdx.x & 63;
  int l15 = lane & 15, quad = lane >> 4;
  int bbase = blockIdx.x * 128 + wave * 32;
  int t0 = bbase + l15;                    // tail plane rows (coalesced, no gather)
  int t1 = bbase + 16 + l15;

  f32x4 acc[2][8];
  #pragma unroll
  for (int m = 0; m < 2; ++m)
    #pragma unroll
    for (int n = 0; n < 8; ++n) acc[m][n] = f32x4{0.f, 0.f, 0.f, 0.f};

  union U { uint4 u; bf16x8 h; };
  #pragma unroll
  for (int ks = 0; ks < 4; ++ks) {
    int eoff = ks * 32 + quad * 8;
    U a0, a1;
    a0.u = *(const uint4*)(pth + (size_t)t0 * DIM + eoff);
    a1.u = *(const uint4*)(pth + (size_t)t1 * DIM + eoff);
    #pragma unroll
    for (int nt = 0; nt < 8; ++nt) {
      U b; b.u = *(const uint4*)(&Qs[(nt * 16 + l15) * QPAD + eoff]);
      acc[0][nt] = __builtin_amdgcn_mfma_f32_16x16x32_bf16(a0.h, b.h, acc[0][nt], 0, 0, 0);
      acc[1][nt] = __builtin_amdgcn_mfma_f32_16x16x32_bf16(a1.h, b.h, acc[1][nt], 0, 0, 0);
    }
  }

  #pragma unroll
  for (int m = 0; m < 2; ++m) {
    #pragma unroll
    for (int reg = 0; reg < 4; ++reg) {
      int bl = bbase + m * 16 + quad * 4 + reg;             // batch index == head plane row
      float s = 0.f;
      #pragma unroll
      for (int nt = 0; nt < 8; ++nt)
        s += pf[(size_t)bl * DIM + nt * 16 + l15] * acc[m][nt][reg];   // head = fp32 plane
      #pragma unroll
      for (int off = 1; off < 16; off <<= 1) s += __shfl_xor(s, off, 64);
      if (l15 == 0) out[(size_t)bl * N_REL + r] = s;
    }
  }
}

// ---------------- launch ----------------

extern "C" void kernel_launch(void* const* d_in, const int* in_sizes, int n_in,
                              void* d_out, int out_size, void* d_ws, size_t ws_size,
                              hipStream_t stream) {
  (void)in_sizes; (void)n_in; (void)out_size; (void)ws_size;
  const float* init_emb = (const float*)d_in[0];
  const float* W1  = (const float*)d_in[1];
  const float* b1  = (const float*)d_in[2];
  const float* W2  = (const float*)d_in[3];
  const float* b2  = (const float*)d_in[4];
  const float* Rel = (const float*)d_in[5];
  const float* M   = (const float*)d_in[6];
  const int* head  = (const int*)d_in[7];
  const int* tail  = (const int*)d_in[8];
  const int* src   = (const int*)d_in[9];
  const int* dst   = src + N_EDGES;
  float* out = (float*)d_out;

  char* p = (char*)d_ws;
  auto alloc = [&](size_t bytes) { char* q = p; p += (bytes + 511) & ~(size_t)511; return q; };
  unsigned int* pcnt = (unsigned int*)alloc((size_t)NP * 4);                   // atomic partition counters
  unsigned int* pe = (unsigned int*)alloc((size_t)NP * PCAP * 4);              // 6.4 MB packed edges
  int*   cnt  = (int*)alloc((size_t)N_NODES * 4);
  float* dv   = (float*)alloc((size_t)(N_NODES + 1) * 4);                      // +1 sentinel
  int*   mask = (int*)alloc((size_t)(N_NODES + 1) * 4);                        // needed-node mask
  int*   list = (int*)alloc((size_t)N_NODES * 4);                              // compacted needed nodes
  int*   Mcount = (int*)alloc(64);
  unsigned short* esrc = (unsigned short*)alloc((size_t)N_NODES * CAP * 2);    // 6.4 MB u16 buckets
  float* edv = (float*)alloc((size_t)N_NODES * CAP * 4);                       // 12.8 MB per-slot dinv
  unsigned short* hs    = (unsigned short*)alloc((size_t)NSLAB * PSTR * 2);    // slab-major h1 (+zero row)
  unsigned short* hbuf2 = (unsigned short*)alloc((size_t)(N_NODES + 1) * DIM * 2);  // +1 zero row
  float*          pf    = (float*)alloc((size_t)BATCH * DIM * 4);              // head plane fp32
  unsigned short* pth   = (unsigned short*)alloc((size_t)BATCH * DIM * 2);     // tail plane bf16 hi
  unsigned short* Qbf   = (unsigned short*)alloc((size_t)N_REL * DIM * DIM * 2);
  unsigned short* W1th  = (unsigned short*)alloc((size_t)DIM * DIM * 2);
  unsigned short* W1tl  = (unsigned short*)alloc((size_t)DIM * DIM * 2);
  unsigned short* W2th  = (unsigned short*)alloc((size_t)DIM * DIM * 2);
  unsigned short* W2tl  = (unsigned short*)alloc((size_t)DIM * DIM * 2);
  unsigned short* Mth   = (unsigned short*)alloc((size_t)DIM * DIM * 2);

  // 0: weight prep + sentinel zeroing + pcnt/mask/Mcount zero
  k_prep<<<DIM * DIM / 256, 256, 0, stream>>>(W1, W2, M, W1th, W1tl, W2th, W2tl, Mth,
                                              hs, hbuf2, dv, pcnt, mask, Mcount);
  // 1: edge build (regs across hist->reserve->scatter) || decoder TQ || gemm1
  k_mega1<<<EB + G_TQ + G_GEMM, 256, 0, stream>>>(src, dst, pcnt, pe, Rel, Mth, Qbf,
                                                  init_emb, W1th, W1tl, hs);
  // 2: per-partition bucket fill (u16, pad-to-8) -> esrc + cnt + dinv
  k_build<<<NP, 256, 0, stream>>>(pe, pcnt, esrc, cnt, dv);
  // 3: mark needed set (batch nodes + neighbors)
  k_mark<<<(2 * BATCH + 7) / 8, 256, 0, stream>>>(head, tail, esrc, cnt, mask);
  // 4: compact mask -> list (Mcount)
  k_compact<<<(N_NODES + 255) / 256, 256, 0, stream>>>(mask, list, Mcount);
  // 5: pre-gather per-slot dinv -> edv (list-driven)
  k_edv<<<(N_NODES + 31) / 32, 256, 0, stream>>>(list, Mcount, esrc, cnt, dv, edv);
  // 6: fused agg1 + gemm2 (list-driven; both slab planes; MFMA from LDS)
  k_agg_gemm2<<<(N_NODES + 15) / 16, 256, 0, stream>>>(hs, cnt, dv, esrc, edv, b1, W2th, W2tl,
                                                       list, Mcount, hbuf2);
  // 7: agg2 only at batch positions -> compact planes (head fp32, tail bf16)
  k_agg_batch<<<(2 * BATCH + 7) / 8, 256, 0, stream>>>(hbuf2, cnt, dv, esrc, edv, b2, head, tail, pf, pth);
  // 8: predict (coalesced reads from compact planes)
  k_predict_mfma<<<dim3(BATCH / 128, N_REL), 256, 0, stream>>>(pf, pth, Qbf, out);
}

// Round 13
// 209.705 us; speedup vs baseline: 1.0567x; 1.0210x over previous
//
#include <hip/hip_runtime.h>

#define N_NODES 50000
#define N_EDGES 800000
#define DIM 128
#define N_REL 86
#define BATCH 2048
#define CAP 64               // per-node bucket capacity; max deg ~45 for Poisson(16)
#define ZROW N_NODES         // sentinel row: zeroed embedding row, dv[ZROW]=0 (fits u16)

#define NP 196               // partitions by dst>>8 (256 nodes each; ceil(50000/256))
#define EB 196               // edge blocks for build (4096 edges each)
#define PCAP 8192            // partition edge capacity (mean 4096, sigma 64)

#define NSLAB 2              // 64-dim slabs; slab-major planes, 6.4 MB each
#define PSTR ((size_t)(N_NODES + 1) * 64)                       // ushorts per slab plane

using bf16x8 = __attribute__((ext_vector_type(8))) short;
using f32x4  = __attribute__((ext_vector_type(4))) float;

// float -> bf16 round-to-nearest-even (finite inputs)
static __device__ __forceinline__ unsigned short f2bf(float f) {
  union { float f; unsigned int i; } v; v.f = f;
  unsigned int x = v.i;
  unsigned int r = x + 0x7FFFu + ((x >> 16) & 1u);
  return (unsigned short)(r >> 16);
}
static __device__ __forceinline__ float bf2f(unsigned short u) {
  union { unsigned int i; float f; } v;
  v.i = ((unsigned int)u) << 16;
  return v.f;
}

#define G_TQ    172           // 86 relations x 2 d-blocks
#define G_GEMM  391           // ceil(50000/128)
#define TPAD 136              // 128+8 bf16: 272 B row stride -> 2-way bank alias (free)
#define QPAD 136
#define APAD 136

// ---------------- kernel 0: weight prep + sentinel zeroing + pcnt/mask/bmask/Mcount zero ----------------

__global__ __launch_bounds__(256) void k_prep(const float* __restrict__ W1, const float* __restrict__ W2,
                                              const float* __restrict__ M,
                                              unsigned short* __restrict__ W1th, unsigned short* __restrict__ W1tl,
                                              unsigned short* __restrict__ W2th, unsigned short* __restrict__ W2tl,
                                              unsigned short* __restrict__ Mth,
                                              unsigned short* __restrict__ hs,
                                              unsigned short* __restrict__ hbuf2,
                                              float* __restrict__ dv,
                                              unsigned int* __restrict__ pcnt,
                                              int* __restrict__ mask,
                                              int* __restrict__ bmask,
                                              int* __restrict__ Mcount) {
  int g = blockIdx.x * 256 + threadIdx.x;          // 16384 threads = DIM*DIM
  if (g < NP) pcnt[g] = 0u;                        // partition atomic counters
  #pragma unroll
  for (int q = 0; q < 4; ++q) {                    // zero needed-mask + batch-mask (N+1 entries)
    int idx = g + q * 16384;
    if (idx <= N_NODES) { mask[idx] = 0; bmask[idx] = 0; }
  }
  // zero sentinel rows (gather pads resolve to ZROW; must be 0.0 not garbage/NaN)
  if (g < 32) {                                    // 2 slab planes x 16 ushort4
    ushort4 z = {0, 0, 0, 0};
    ((ushort4*)(hs + (size_t)(g >> 4) * PSTR))[(size_t)ZROW * 16 + (g & 15)] = z;
  }
  if (g >= 32 && g < 64) {                         // hbuf2 row (32 ushort4)
    ushort4 z = {0, 0, 0, 0};
    ((ushort4*)hbuf2)[(size_t)ZROW * 32 + (g - 32)] = z;
  }
  if (g == 64) dv[ZROW] = 0.f;
  if (g == 65) *Mcount = 0;
  int k = g >> 7, n = g & 127;
  int t = n * DIM + k;
  float w1 = W1[g];
  unsigned short h1 = f2bf(w1);
  W1th[t] = h1;
  W1tl[t] = f2bf(w1 - bf2f(h1));
  float w2 = W2[g];
  unsigned short h2 = f2bf(w2);
  W2th[t] = h2;
  W2tl[t] = f2bf(w2 - bf2f(h2));
  Mth[t] = f2bf(M[g]);
}

// ---------------- bmark: seed batch-node masks (runs after prep's zeroing) ----------------

__global__ __launch_bounds__(256) void k_bmark(const int* __restrict__ head, const int* __restrict__ tail,
                                               int* __restrict__ mask, int* __restrict__ bmask) {
  int i = blockIdx.x * 256 + threadIdx.x;          // 4096 threads
  int node = (i < BATCH) ? head[i] : tail[i - BATCH];
  bmask[node] = 1;
  mask[node] = 1;
}

// ---------------- mega1: edge build (regs held across hist -> reserve -> scatter) + neighbor marking
//                         ||  decoder TQ  ||  gemm1 (slab-major out) ----------------
// pe entry: (dst & 255) << 17 | src     (src < 50000 < 2^17)

__global__ __launch_bounds__(256) void k_mega1(const int* __restrict__ src, const int* __restrict__ dst,
                                               unsigned int* __restrict__ pcnt,
                                               unsigned int* __restrict__ pe,
                                               const int* __restrict__ bmask,
                                               int* __restrict__ mask,
                                               const float* __restrict__ Rel,
                                               const unsigned short* __restrict__ Mth,
                                               unsigned short* __restrict__ Qbf,
                                               const float* __restrict__ x,
                                               const unsigned short* __restrict__ W1th,
                                               const unsigned short* __restrict__ W1tl,
                                               unsigned short* __restrict__ hs) {
  __shared__ __align__(16) unsigned char smem[64 * TPAD * 2];   // max(hist 784B, Ts 17408B)
  int bid = blockIdx.x;
  union U { uint4 u; bf16x8 h; };

  if (bid < EB) {
    unsigned int* hist = (unsigned int*)smem;
    int t = threadIdx.x;
    if (t < NP) hist[t] = 0u;
    __syncthreads();
    // ---- load edges ONCE into registers, histogram + neighbor-mark ----
    int4 sA[4], dA[4];
    #pragma unroll
    for (int j = 0; j < 4; ++j) {
      int i0 = bid * 4096 + j * 1024 + t * 4;
      if (i0 < N_EDGES) {
        sA[j] = *(const int4*)(src + i0);
        dA[j] = *(const int4*)(dst + i0);
        atomicAdd(&hist[dA[j].x >> 8], 1u);
        atomicAdd(&hist[dA[j].y >> 8], 1u);
        atomicAdd(&hist[dA[j].z >> 8], 1u);
        atomicAdd(&hist[dA[j].w >> 8], 1u);
        // neighbor discovery: src of any edge into a batch node is needed for layer 2
        if (bmask[dA[j].x]) mask[sA[j].x] = 1;
        if (bmask[dA[j].y]) mask[sA[j].y] = 1;
        if (bmask[dA[j].z]) mask[sA[j].z] = 1;
        if (bmask[dA[j].w]) mask[sA[j].w] = 1;
      }
    }
    __syncthreads();
    // ---- reserve global ranges: one atomic per (block, bin) ----
    if (t < NP) {
      unsigned int c = hist[t];
      unsigned int base = c ? atomicAdd(&pcnt[t], c) : 0u;
      hist[t] = (unsigned int)t * PCAP + base;     // becomes this block's write cursor
    }
    __syncthreads();
    // ---- scatter from registers via LDS cursor ----
    #pragma unroll
    for (int j = 0; j < 4; ++j) {
      int i0 = bid * 4096 + j * 1024 + t * 4;
      if (i0 < N_EDGES) {
        int b0 = dA[j].x >> 8, b1 = dA[j].y >> 8, b2 = dA[j].z >> 8, b3 = dA[j].w >> 8;
        unsigned int p0 = atomicAdd(&hist[b0], 1u);
        unsigned int p1 = atomicAdd(&hist[b1], 1u);
        unsigned int p2 = atomicAdd(&hist[b2], 1u);
        unsigned int p3 = atomicAdd(&hist[b3], 1u);
        if (p0 < (unsigned int)(b0 + 1) * PCAP) pe[p0] = ((unsigned)(dA[j].x & 255) << 17) | (unsigned)sA[j].x;
        if (p1 < (unsigned int)(b1 + 1) * PCAP) pe[p1] = ((unsigned)(dA[j].y & 255) << 17) | (unsigned)sA[j].y;
        if (p2 < (unsigned int)(b2 + 1) * PCAP) pe[p2] = ((unsigned)(dA[j].z & 255) << 17) | (unsigned)sA[j].z;
        if (p3 < (unsigned int)(b3 + 1) * PCAP) pe[p3] = ((unsigned)(dA[j].w & 255) << 17) | (unsigned)sA[j].w;
      }
    }
    return;
  }

  int wave = threadIdx.x >> 6, lane = threadIdx.x & 63;
  int l15 = lane & 15, quad = lane >> 4;

  if (bid < EB + G_TQ) {
    // ---- decoder precompute: T_r = Rel_r @ M (LDS), Q_r = T_r @ Rel_r^T ----
    unsigned short* Ts = (unsigned short*)smem;
    int tb = bid - EB;                       // [0, 172)
    int r = tb >> 1, dblk = tb & 1;
    const float* Rr = Rel + (size_t)r * DIM * DIM;
    unsigned short* Qr = Qbf + (size_t)r * DIM * DIM;
    int dw = dblk * 64 + wave * 16;
    f32x4 acc[8];
    #pragma unroll
    for (int nt = 0; nt < 8; ++nt) acc[nt] = f32x4{0.f, 0.f, 0.f, 0.f};
    #pragma unroll
    for (int ks = 0; ks < 4; ++ks) {
      int k0 = ks * 32 + quad * 8;
      const float* ap = Rr + (size_t)(dw + l15) * DIM + k0;
      float av[8];
      *(float4*)(av)     = *(const float4*)(ap);
      *(float4*)(av + 4) = *(const float4*)(ap + 4);
      bf16x8 a;
      #pragma unroll
      for (int j = 0; j < 8; ++j) a[j] = (short)f2bf(av[j]);
      #pragma unroll
      for (int nt = 0; nt < 8; ++nt) {
        U b; b.u = *(const uint4*)(Mth + (nt * 16 + l15) * DIM + k0);
        acc[nt] = __builtin_amdgcn_mfma_f32_16x16x32_bf16(a, b.h, acc[nt], 0, 0, 0);
      }
    }
    #pragma unroll
    for (int nt = 0; nt < 8; ++nt)
      #pragma unroll
      for (int reg = 0; reg < 4; ++reg)
        Ts[(wave * 16 + quad * 4 + reg) * TPAD + nt * 16 + l15] = f2bf(acc[nt][reg]);
    __syncthreads();
    f32x4 qacc[8];
    #pragma unroll
    for (int nt = 0; nt < 8; ++nt) qacc[nt] = f32x4{0.f, 0.f, 0.f, 0.f};
    #pragma unroll
    for (int ks = 0; ks < 4; ++ks) {
      int k0 = ks * 32 + quad * 8;
      U a; a.u = *(const uint4*)(Ts + (wave * 16 + l15) * TPAD + k0);
      #pragma unroll
      for (int nt = 0; nt < 8; ++nt) {
        const float* bp = Rr + (size_t)(nt * 16 + l15) * DIM + k0;
        float bv[8];
        *(float4*)(bv)     = *(const float4*)(bp);
        *(float4*)(bv + 4) = *(const float4*)(bp + 4);
        bf16x8 b;
        #pragma unroll
        for (int j = 0; j < 8; ++j) b[j] = (short)f2bf(bv[j]);
        qacc[nt] = __builtin_amdgcn_mfma_f32_16x16x32_bf16(a.h, b, qacc[nt], 0, 0, 0);
      }
    }
    #pragma unroll
    for (int nt = 0; nt < 8; ++nt)
      #pragma unroll
      for (int reg = 0; reg < 4; ++reg)
        Qr[(size_t)(dw + quad * 4 + reg) * DIM + nt * 16 + l15] = f2bf(qacc[nt][reg]);
    return;
  }

  // ---- node GEMM layer 1: hs = slab-major(x @ W1) (hi/lo 3-term, bf16 out) ----
  int r0 = (bid - EB - G_TQ) * 128 + wave * 32;
  f32x4 acc[2][8];
  #pragma unroll
  for (int mt = 0; mt < 2; ++mt)
    #pragma unroll
    for (int nt = 0; nt < 8; ++nt) acc[mt][nt] = f32x4{0.f, 0.f, 0.f, 0.f};
  #pragma unroll
  for (int ks = 0; ks < 4; ++ks) {
    int k0 = ks * 32 + quad * 8;
    bf16x8 ah[2], al[2];
    #pragma unroll
    for (int mt = 0; mt < 2; ++mt) {
      int row = r0 + mt * 16 + l15;
      row = (row < N_NODES) ? row : (N_NODES - 1);
      const float* xp = x + (size_t)row * DIM + k0;
      float xv[8];
      *(float4*)(xv)     = *(const float4*)(xp);
      *(float4*)(xv + 4) = *(const float4*)(xp + 4);
      #pragma unroll
      for (int j = 0; j < 8; ++j) {
        unsigned short h = f2bf(xv[j]);
        ah[mt][j] = (short)h;
        al[mt][j] = (short)f2bf(xv[j] - bf2f(h));
      }
    }
    #pragma unroll
    for (int nt = 0; nt < 8; ++nt) {
      U bh, bl;
      bh.u = *(const uint4*)(W1th + (nt * 16 + l15) * DIM + k0);
      bl.u = *(const uint4*)(W1tl + (nt * 16 + l15) * DIM + k0);
      #pragma unroll
      for (int mt = 0; mt < 2; ++mt) {
        acc[mt][nt] = __builtin_amdgcn_mfma_f32_16x16x32_bf16(ah[mt], bh.h, acc[mt][nt], 0, 0, 0);
        acc[mt][nt] = __builtin_amdgcn_mfma_f32_16x16x32_bf16(al[mt], bh.h, acc[mt][nt], 0, 0, 0);
        acc[mt][nt] = __builtin_amdgcn_mfma_f32_16x16x32_bf16(ah[mt], bl.h, acc[mt][nt], 0, 0, 0);
      }
    }
  }
  #pragma unroll
  for (int mt = 0; mt < 2; ++mt)
    #pragma unroll
    for (int reg = 0; reg < 4; ++reg) {
      int row = r0 + mt * 16 + quad * 4 + reg;
      if (row < N_NODES) {
        #pragma unroll
        for (int nt = 0; nt < 8; ++nt)
          hs[(size_t)(nt >> 2) * PSTR + (size_t)row * 64 + (nt & 3) * 16 + l15] = f2bf(acc[mt][nt][reg]);
      }
    }
}

// ---------------- build: per-partition bucket fill (u16) + pad-to-8 + cnt + dinv + fused compact ----------------

__global__ __launch_bounds__(256) void k_build(const unsigned int* __restrict__ pe,
                                               const unsigned int* __restrict__ partCnt,
                                               unsigned short* __restrict__ esrc, int* __restrict__ cnt,
                                               float* __restrict__ dv,
                                               const int* __restrict__ mask,
                                               int* __restrict__ list,
                                               int* __restrict__ Mcount) {
  __shared__ unsigned int c256[256];
  __shared__ int sd[256];
  __shared__ int sbase;
  int p = blockIdx.x, t = threadIdx.x;
  c256[t] = 0u;
  __syncthreads();
  int m = min((int)partCnt[p], PCAP);
  for (int i = t; i < m; i += 256) {
    unsigned int e = pe[(size_t)p * PCAP + i];
    unsigned int local = e >> 17;
    unsigned int s = e & 0x1FFFFu;
    unsigned int slot = atomicAdd(&c256[local], 1u);
    int node = p * 256 + (int)local;
    if (slot < CAP) esrc[(size_t)node * CAP + slot] = (unsigned short)s;
  }
  __syncthreads();
  int node = p * 256 + t;
  if (node < N_NODES) {
    int c = (int)c256[t];
    cnt[node] = c;
    dv[node] = rsqrtf((float)(c + 1));
    int padded = min((c + 7) & ~7, CAP);          // pad bucket to multiple of 8
    for (int s = c; s < padded; ++s) esrc[(size_t)node * CAP + s] = (unsigned short)ZROW;
  }
  // ---- fused compact: needed-mask -> list (block p owns nodes p*256..p*256+255) ----
  int nm = (node < N_NODES) ? mask[node] : 0;
  sd[t] = nm;
  __syncthreads();
  for (int off = 1; off < 256; off <<= 1) {
    int y = (t >= off) ? sd[t - off] : 0;
    __syncthreads();
    sd[t] += y;
    __syncthreads();
  }
  if (t == 255) sbase = atomicAdd(Mcount, sd[255]);
  __syncthreads();
  if (nm) list[sbase + sd[t] - 1] = node;
}

// ---------------- edv: pre-gather per-edge-slot dinv, list-driven ----------------

__global__ __launch_bounds__(256) void k_edv(const int* __restrict__ list,
                                             const int* __restrict__ Mcount,
                                             const unsigned short* __restrict__ esrc,
                                             const int* __restrict__ cnt,
                                             const float* __restrict__ dv,
                                             float* __restrict__ edv) {
  int j = blockIdx.x * 32 + (threadIdx.x >> 3);
  if (j >= *Mcount) return;
  int node = list[j];
  int s0 = (threadIdx.x & 7) * 8;                 // this lane's 8 slots
  int padded = min((cnt[node] + 7) & ~7, CAP);
  if (s0 >= padded) return;                       // garbage slots never read downstream
  const unsigned short* eb = esrc + (size_t)node * CAP + s0;
  ushort4 a = *(const ushort4*)(eb);
  ushort4 b = *(const ushort4*)(eb + 4);
  float4 da, db;
  da.x = dv[min((int)a.x, ZROW)]; da.y = dv[min((int)a.y, ZROW)];
  da.z = dv[min((int)a.z, ZROW)]; da.w = dv[min((int)a.w, ZROW)];
  db.x = dv[min((int)b.x, ZROW)]; db.y = dv[min((int)b.y, ZROW)];
  db.z = dv[min((int)b.z, ZROW)]; db.w = dv[min((int)b.w, ZROW)];
  *(float4*)(edv + (size_t)node * CAP + s0)     = da;
  *(float4*)(edv + (size_t)node * CAP + s0 + 4) = db;
}

// ---------------- fused agg1 + gemm2: LIST-DRIVEN, 16 nodes/block; 32 lanes/node
//                  (16 per slab plane); each edge visited once; MFMA @ W2 from LDS ----------------

__global__ __launch_bounds__(256) void k_agg_gemm2(const unsigned short* __restrict__ hs,
                                                   const int* __restrict__ cnt,
                                                   const float* __restrict__ dv,
                                                   const unsigned short* __restrict__ esrc,
                                                   const float* __restrict__ edv,
                                                   const float* __restrict__ bias,
                                                   const unsigned short* __restrict__ Wth,
                                                   const unsigned short* __restrict__ Wtl,
                                                   const int* __restrict__ list,
                                                   const int* __restrict__ Mcount,
                                                   unsigned short* __restrict__ out) {
  __shared__ __align__(16) unsigned short Ah[16 * APAD];
  __shared__ __align__(16) unsigned short Al[16 * APAD];
  __shared__ int nodeIds[16];
  int Mn = *Mcount;
  int base = blockIdx.x * 16;
  if (base >= Mn) return;
  if (threadIdx.x < 16) {
    int j = base + threadIdx.x;
    nodeIds[threadIdx.x] = (j < Mn) ? list[j] : ZROW;
  }
  __syncthreads();

  int warp = threadIdx.x >> 5, lane32 = threadIdx.x & 31;
  int half = lane32 >> 4, lane16 = lane32 & 15;   // half selects slab plane
  const ushort4* h4 = (const ushort4*)(hs + (size_t)half * PSTR);   // 16 ushort4 per row-slab

  #pragma unroll
  for (int i = 0; i < 2; ++i) {
    int row = warp * 2 + i;
    int node = nodeIds[row];
    if (node == ZROW) {                           // boundary pad: keep LDS defined, skip work
      ushort4 z = {0, 0, 0, 0};
      *(ushort4*)(&Ah[row * APAD + lane32 * 4]) = z;
      *(ushort4*)(&Al[row * APAD + lane32 * 4]) = z;
      continue;
    }
    int deg = cnt[node];
    int end = min((deg + 7) & ~7, CAP);           // padded multiple of 8
    float di = dv[node];
    ushort4 hv = h4[(size_t)node * 16 + lane16];
    float ax = di * bf2f(hv.x), ay = di * bf2f(hv.y), az = di * bf2f(hv.z), aw = di * bf2f(hv.w);
    float bx = 0.f, by = 0.f, bz = 0.f, bw = 0.f;
    const unsigned short* eb = esrc + (size_t)node * CAP;
    const float* ev = edv + (size_t)node * CAP;
    for (int e = 0; e < end; e += 8) {
      ushort4 iA = *(const ushort4*)(eb + e);     // broadcast within 32-lane group
      ushort4 iB = *(const ushort4*)(eb + e + 4);
      float4 dA = *(const float4*)(ev + e);       // sequential, broadcast within group
      float4 dB = *(const float4*)(ev + e + 4);
      ushort4 v0 = h4[(size_t)iA.x * 16 + lane16];
      ushort4 v1 = h4[(size_t)iA.y * 16 + lane16];
      ushort4 v2 = h4[(size_t)iA.z * 16 + lane16];
      ushort4 v3 = h4[(size_t)iA.w * 16 + lane16];
      ushort4 v4 = h4[(size_t)iB.x * 16 + lane16];
      ushort4 v5 = h4[(size_t)iB.y * 16 + lane16];
      ushort4 v6 = h4[(size_t)iB.z * 16 + lane16];
      ushort4 v7 = h4[(size_t)iB.w * 16 + lane16];
      ax = fmaf(dA.x, bf2f(v0.x), ax); ay = fmaf(dA.x, bf2f(v0.y), ay); az = fmaf(dA.x, bf2f(v0.z), az); aw = fmaf(dA.x, bf2f(v0.w), aw);
      bx = fmaf(dA.y, bf2f(v1.x), bx); by = fmaf(dA.y, bf2f(v1.y), by); bz = fmaf(dA.y, bf2f(v1.z), bz); bw = fmaf(dA.y, bf2f(v1.w), bw);
      ax = fmaf(dA.z, bf2f(v2.x), ax); ay = fmaf(dA.z, bf2f(v2.y), ay); az = fmaf(dA.z, bf2f(v2.z), az); aw = fmaf(dA.z, bf2f(v2.w), aw);
      bx = fmaf(dA.w, bf2f(v3.x), bx); by = fmaf(dA.w, bf2f(v3.y), by); bz = fmaf(dA.w, bf2f(v3.z), bz); bw = fmaf(dA.w, bf2f(v3.w), bw);
      ax = fmaf(dB.x, bf2f(v4.x), ax); ay = fmaf(dB.x, bf2f(v4.y), ay); az = fmaf(dB.x, bf2f(v4.z), az); aw = fmaf(dB.x, bf2f(v4.w), aw);
      bx = fmaf(dB.y, bf2f(v5.x), bx); by = fmaf(dB.y, bf2f(v5.y), by); bz = fmaf(dB.y, bf2f(v5.z), bz); bw = fmaf(dB.y, bf2f(v5.w), bw);
      ax = fmaf(dB.z, bf2f(v6.x), ax); ay = fmaf(dB.z, bf2f(v6.y), ay); az = fmaf(dB.z, bf2f(v6.z), az); aw = fmaf(dB.z, bf2f(v6.w), aw);
      bx = fmaf(dB.w, bf2f(v7.x), bx); by = fmaf(dB.w, bf2f(v7.y), by); bz = fmaf(dB.w, bf2f(v7.z), bz); bw = fmaf(dB.w, bf2f(v7.w), bw);
    }
    ax += bx; ay += by; az += bz; aw += bw;
    float4 bb = ((const float4*)bias)[lane32];    // dims lane32*4..+3 = half*64 + lane16*4
    float vx = fmaf(di, ax, bb.x), vy = fmaf(di, ay, bb.y);
    float vz = fmaf(di, az, bb.z), vw = fmaf(di, aw, bb.w);
    ushort4 hi4, lo4;
    hi4.x = f2bf(vx); lo4.x = f2bf(vx - bf2f(hi4.x));
    hi4.y = f2bf(vy); lo4.y = f2bf(vy - bf2f(hi4.y));
    hi4.z = f2bf(vz); lo4.z = f2bf(vz - bf2f(hi4.z));
    hi4.w = f2bf(vw); lo4.w = f2bf(vw - bf2f(hi4.w));
    *(ushort4*)(&Ah[row * APAD + lane32 * 4]) = hi4;
    *(ushort4*)(&Al[row * APAD + lane32 * 4]) = lo4;
  }
  __syncthreads();

  // GEMM phase: 4 wave64s, each computes rows 0..15 x cols [wave*32, wave*32+32)
  int wave = threadIdx.x >> 6, l = threadIdx.x & 63;
  int l15 = l & 15, quad = l >> 4;
  union U { uint4 u; bf16x8 h; };
  f32x4 acc[2];
  #pragma unroll
  for (int nt = 0; nt < 2; ++nt) acc[nt] = f32x4{0.f, 0.f, 0.f, 0.f};
  #pragma unroll
  for (int ks = 0; ks < 4; ++ks) {
    int k0 = ks * 32 + quad * 8;
    U ah, al;
    ah.u = *(const uint4*)(&Ah[l15 * APAD + k0]);
    al.u = *(const uint4*)(&Al[l15 * APAD + k0]);
    #pragma unroll
    for (int nt = 0; nt < 2; ++nt) {
      int n0 = wave * 32 + nt * 16;
      U bh, bl;
      bh.u = *(const uint4*)(Wth + (n0 + l15) * DIM + k0);
      bl.u = *(const uint4*)(Wtl + (n0 + l15) * DIM + k0);
      acc[nt] = __builtin_amdgcn_mfma_f32_16x16x32_bf16(ah.h, bh.h, acc[nt], 0, 0, 0);
      acc[nt] = __builtin_amdgcn_mfma_f32_16x16x32_bf16(al.h, bh.h, acc[nt], 0, 0, 0);
      acc[nt] = __builtin_amdgcn_mfma_f32_16x16x32_bf16(ah.h, bl.h, acc[nt], 0, 0, 0);
    }
  }
  #pragma unroll
  for (int reg = 0; reg < 4; ++reg) {
    int node = nodeIds[quad * 4 + reg];
    if (node != ZROW) {                           // keep hbuf2[ZROW] zeroed for pads
      #pragma unroll
      for (int nt = 0; nt < 2; ++nt)
        out[(size_t)node * DIM + wave * 32 + nt * 16 + l15] = f2bf(acc[nt][reg]);
    }
  }
}

// ---------------- full-row aggregation core (agg_batch; hbuf2 row-major, sequential edv) ----------------

static __device__ __forceinline__ float4 agg_compute(const unsigned short* __restrict__ h,
                                                     const int* __restrict__ cnt,
                                                     const float* __restrict__ dv,
                                                     const unsigned short* __restrict__ esrc,
                                                     const float* __restrict__ edv,
                                                     const float* __restrict__ bias,
                                                     int node, int lane) {
  const ushort4* h4 = (const ushort4*)h;
  int deg = cnt[node];
  int end = min((deg + 7) & ~7, CAP);              // padded length, multiple of 8
  float di = dv[node];
  ushort4 hv = h4[(size_t)node * 32 + lane];
  float ax = di * bf2f(hv.x), ay = di * bf2f(hv.y), az = di * bf2f(hv.z), aw = di * bf2f(hv.w);
  float bx = 0.f, by = 0.f, bz = 0.f, bw = 0.f;
  const unsigned short* eb = esrc + (size_t)node * CAP;
  const float* ev = edv + (size_t)node * CAP;
  for (int e = 0; e < end; e += 8) {
    ushort4 iA = *(const ushort4*)(eb + e);
    ushort4 iB = *(const ushort4*)(eb + e + 4);
    float4 dA = *(const float4*)(ev + e);
    float4 dB = *(const float4*)(ev + e + 4);
    ushort4 v0 = h4[(size_t)iA.x * 32 + lane];
    ushort4 v1 = h4[(size_t)iA.y * 32 + lane];
    ushort4 v2 = h4[(size_t)iA.z * 32 + lane];
    ushort4 v3 = h4[(size_t)iA.w * 32 + lane];
    ushort4 v4 = h4[(size_t)iB.x * 32 + lane];
    ushort4 v5 = h4[(size_t)iB.y * 32 + lane];
    ushort4 v6 = h4[(size_t)iB.z * 32 + lane];
    ushort4 v7 = h4[(size_t)iB.w * 32 + lane];
    ax = fmaf(dA.x, bf2f(v0.x), ax); ay = fmaf(dA.x, bf2f(v0.y), ay); az = fmaf(dA.x, bf2f(v0.z), az); aw = fmaf(dA.x, bf2f(v0.w), aw);
    bx = fmaf(dA.y, bf2f(v1.x), bx); by = fmaf(dA.y, bf2f(v1.y), by); bz = fmaf(dA.y, bf2f(v1.z), bz); bw = fmaf(dA.y, bf2f(v1.w), bw);
    ax = fmaf(dA.z, bf2f(v2.x), ax); ay = fmaf(dA.z, bf2f(v2.y), ay); az = fmaf(dA.z, bf2f(v2.z), az); aw = fmaf(dA.z, bf2f(v2.w), aw);
    bx = fmaf(dA.w, bf2f(v3.x), bx); by = fmaf(dA.w, bf2f(v3.y), by); bz = fmaf(dA.w, bf2f(v3.z), bz); bw = fmaf(dA.w, bf2f(v3.w), bw);
    ax = fmaf(dB.x, bf2f(v4.x), ax); ay = fmaf(dB.x, bf2f(v4.y), ay); az = fmaf(dB.x, bf2f(v4.z), az); aw = fmaf(dB.x, bf2f(v4.w), aw);
    bx = fmaf(dB.y, bf2f(v5.x), bx); by = fmaf(dB.y, bf2f(v5.y), by); bz = fmaf(dB.y, bf2f(v5.z), bz); bw = fmaf(dB.y, bf2f(v5.w), bw);
    ax = fmaf(dB.z, bf2f(v6.x), ax); ay = fmaf(dB.z, bf2f(v6.y), ay); az = fmaf(dB.z, bf2f(v6.z), az); aw = fmaf(dB.z, bf2f(v6.w), aw);
    bx = fmaf(dB.w, bf2f(v7.x), bx); by = fmaf(dB.w, bf2f(v7.y), by); bz = fmaf(dB.w, bf2f(v7.z), bz); bw = fmaf(dB.w, bf2f(v7.w), bw);
  }
  ax += bx; ay += by; az += bz; aw += bw;
  float4 bb = ((const float4*)bias)[lane];
  float4 v;
  v.x = fmaf(di, ax, bb.x); v.y = fmaf(di, ay, bb.y);
  v.z = fmaf(di, az, bb.z); v.w = fmaf(di, aw, bb.w);
  return v;
}

// ---------------- agg2 at batch positions only ----------------
// head rows -> fp32 plane pf[BATCH][128]; tail rows -> bf16 hi plane pth[BATCH][128]

__global__ __launch_bounds__(256) void k_agg_batch(const unsigned short* __restrict__ h,
                                                   const int* __restrict__ cnt,
                                                   const float* __restrict__ dv,
                                                   const unsigned short* __restrict__ esrc,
                                                   const float* __restrict__ edv,
                                                   const float* __restrict__ bias,
                                                   const int* __restrict__ head,
                                                   const int* __restrict__ tail,
                                                   float* __restrict__ pf,
                                                   unsigned short* __restrict__ pth) {
  int pos = blockIdx.x * 8 + (threadIdx.x >> 5);
  if (pos >= 2 * BATCH) return;
  int lane = threadIdx.x & 31;
  int node = (pos < BATCH) ? head[pos] : tail[pos - BATCH];
  float4 v = agg_compute(h, cnt, dv, esrc, edv, bias, node, lane);
  if (pos < BATCH) {
    ((float4*)pf)[(size_t)pos * 32 + lane] = v;
  } else {
    ushort4 hi4 = { f2bf(v.x), f2bf(v.y), f2bf(v.z), f2bf(v.w) };
    ((ushort4*)pth)[(size_t)(pos - BATCH) * 32 + lane] = hi4;
  }
}

// ---------------- predict via MFMA: tail (bf16) @ Q_r, dot with head (fp32) ----------------

__global__ __launch_bounds__(256) void k_predict_mfma(const float* __restrict__ pf,
                                                      const unsigned short* __restrict__ pth,
                                                      const unsigned short* __restrict__ Qbf,
                                                      float* __restrict__ out) {
  __shared__ __align__(16) unsigned short Qs[DIM * QPAD];
  int r = blockIdx.y;
  const unsigned short* Qr = Qbf + (size_t)r * DIM * DIM;
  for (int i = threadIdx.x; i < DIM * DIM / 8; i += 256) {
    int d = i >> 4, c = (i & 15) * 8;
    uint4 v = ((const uint4*)Qr)[i];
    *(uint4*)(&Qs[d * QPAD + c]) = v;
  }
  __syncthreads();
  int wave = threadIdx.x >> 6, lane = threadIdx.x & 63;
  int l15 = lane & 15, quad = lane >> 4;
  int bbase = blockIdx.x * 128 + wave * 32;
  int t0 = bbase + l15;                    // tail plane rows (coalesced, no gather)
  int t1 = bbase + 16 + l15;

  f32x4 acc[2][8];
  #pragma unroll
  for (int m = 0; m < 2; ++m)
    #pragma unroll
    for (int n = 0; n < 8; ++n) acc[m][n] = f32x4{0.f, 0.f, 0.f, 0.f};

  union U { uint4 u; bf16x8 h; };
  #pragma unroll
  for (int ks = 0; ks < 4; ++ks) {
    int eoff = ks * 32 + quad * 8;
    U a0, a1;
    a0.u = *(const uint4*)(pth + (size_t)t0 * DIM + eoff);
    a1.u = *(const uint4*)(pth + (size_t)t1 * DIM + eoff);
    #pragma unroll
    for (int nt = 0; nt < 8; ++nt) {
      U b; b.u = *(const uint4*)(&Qs[(nt * 16 + l15) * QPAD + eoff]);
      acc[0][nt] = __builtin_amdgcn_mfma_f32_16x16x32_bf16(a0.h, b.h, acc[0][nt], 0, 0, 0);
      acc[1][nt] = __builtin_amdgcn_mfma_f32_16x16x32_bf16(a1.h, b.h, acc[1][nt], 0, 0, 0);
    }
  }

  #pragma unroll
  for (int m = 0; m < 2; ++m) {
    #pragma unroll
    for (int reg = 0; reg < 4; ++reg) {
      int bl = bbase + m * 16 + quad * 4 + reg;             // batch index == head plane row
      float s = 0.f;
      #pragma unroll
      for (int nt = 0; nt < 8; ++nt)
        s += pf[(size_t)bl * DIM + nt * 16 + l15] * acc[m][nt][reg];   // head = fp32 plane
      #pragma unroll
      for (int off = 1; off < 16; off <<= 1) s += __shfl_xor(s, off, 64);
      if (l15 == 0) out[(size_t)bl * N_REL + r] = s;
    }
  }
}

// ---------------- launch ----------------

extern "C" void kernel_launch(void* const* d_in, const int* in_sizes, int n_in,
                              void* d_out, int out_size, void* d_ws, size_t ws_size,
                              hipStream_t stream) {
  (void)in_sizes; (void)n_in; (void)out_size; (void)ws_size;
  const float* init_emb = (const float*)d_in[0];
  const float* W1  = (const float*)d_in[1];
  const float* b1  = (const float*)d_in[2];
  const float* W2  = (const float*)d_in[3];
  const float* b2  = (const float*)d_in[4];
  const float* Rel = (const float*)d_in[5];
  const float* M   = (const float*)d_in[6];
  const int* head  = (const int*)d_in[7];
  const int* tail  = (const int*)d_in[8];
  const int* src   = (const int*)d_in[9];
  const int* dst   = src + N_EDGES;
  float* out = (float*)d_out;

  char* p = (char*)d_ws;
  auto alloc = [&](size_t bytes) { char* q = p; p += (bytes + 511) & ~(size_t)511; return q; };
  unsigned int* pcnt = (unsigned int*)alloc((size_t)NP * 4);                   // atomic partition counters
  unsigned int* pe = (unsigned int*)alloc((size_t)NP * PCAP * 4);              // 6.4 MB packed edges
  int*   cnt  = (int*)alloc((size_t)N_NODES * 4);
  float* dv   = (float*)alloc((size_t)(N_NODES + 1) * 4);                      // +1 sentinel
  int*   mask = (int*)alloc((size_t)(N_NODES + 1) * 4);                        // needed-node mask
  int*   bmask = (int*)alloc((size_t)(N_NODES + 1) * 4);                       // batch-node mask (read-only in mega1)
  int*   list = (int*)alloc((size_t)N_NODES * 4);                              // compacted needed nodes
  int*   Mcount = (int*)alloc(64);
  unsigned short* esrc = (unsigned short*)alloc((size_t)N_NODES * CAP * 2);    // 6.4 MB u16 buckets
  float* edv = (float*)alloc((size_t)N_NODES * CAP * 4);                       // 12.8 MB per-slot dinv
  unsigned short* hs    = (unsigned short*)alloc((size_t)NSLAB * PSTR * 2);    // slab-major h1 (+zero row)
  unsigned short* hbuf2 = (unsigned short*)alloc((size_t)(N_NODES + 1) * DIM * 2);  // +1 zero row
  float*          pf    = (float*)alloc((size_t)BATCH * DIM * 4);              // head plane fp32
  unsigned short* pth   = (unsigned short*)alloc((size_t)BATCH * DIM * 2);     // tail plane bf16 hi
  unsigned short* Qbf   = (unsigned short*)alloc((size_t)N_REL * DIM * DIM * 2);
  unsigned short* W1th  = (unsigned short*)alloc((size_t)DIM * DIM * 2);
  unsigned short* W1tl  = (unsigned short*)alloc((size_t)DIM * DIM * 2);
  unsigned short* W2th  = (unsigned short*)alloc((size_t)DIM * DIM * 2);
  unsigned short* W2tl  = (unsigned short*)alloc((size_t)DIM * DIM * 2);
  unsigned short* Mth   = (unsigned short*)alloc((size_t)DIM * DIM * 2);

  // 0: weight prep + sentinel zeroing + pcnt/mask/bmask/Mcount zero
  k_prep<<<DIM * DIM / 256, 256, 0, stream>>>(W1, W2, M, W1th, W1tl, W2th, W2tl, Mth,
                                              hs, hbuf2, dv, pcnt, mask, bmask, Mcount);
  // 1: seed batch-node masks
  k_bmark<<<2 * BATCH / 256, 256, 0, stream>>>(head, tail, mask, bmask);
  // 2: edge build (+ inline neighbor marking) || decoder TQ || gemm1
  k_mega1<<<EB + G_TQ + G_GEMM, 256, 0, stream>>>(src, dst, pcnt, pe, bmask, mask, Rel, Mth, Qbf,
                                                  init_emb, W1th, W1tl, hs);
  // 3: per-partition bucket fill -> esrc + cnt + dinv + fused compact (mask -> list)
  k_build<<<NP, 256, 0, stream>>>(pe, pcnt, esrc, cnt, dv, mask, list, Mcount);
  // 4: pre-gather per-slot dinv -> edv (list-driven)
  k_edv<<<(N_NODES + 31) / 32, 256, 0, stream>>>(list, Mcount, esrc, cnt, dv, edv);
  // 5: fused agg1 + gemm2 (list-driven; both slab planes; MFMA from LDS)
  k_agg_gemm2<<<(N_NODES + 15) / 16, 256, 0, stream>>>(hs, cnt, dv, esrc, edv, b1, W2th, W2tl,
                                                       list, Mcount, hbuf2);
  // 6: agg2 only at batch positions -> compact planes (head fp32, tail bf16)
  k_agg_batch<<<(2 * BATCH + 7) / 8, 256, 0, stream>>>(hbuf2, cnt, dv, esrc, edv, b2, head, tail, pf, pth);
  // 7: predict (coalesced reads from compact planes)
  k_predict_mfma<<<dim3(BATCH / 128, N_REL), 256, 0, stream>>>(pf, pth, Qbf, out);
}

// Round 15
// 207.844 us; speedup vs baseline: 1.0661x; 1.0090x over previous
//
#include <hip/hip_runtime.h>

#define N_NODES 50000
#define N_EDGES 800000
#define DIM 128
#define N_REL 86
#define BATCH 2048
#define CAP 64               // per-node bucket capacity; max deg ~45 for Poisson(16)
#define ZROW N_NODES         // sentinel row: zeroed embedding row, dv[ZROW]=0 (fits u16)

#define NP 196               // partitions by dst>>8 (256 nodes each; ceil(50000/256))
#define EB 196               // edge blocks for build (4096 edges each)
#define PCAP 8192            // partition edge capacity (mean 4096, sigma 64)

#define NSLAB 2              // 64-dim slabs; slab-major planes, 6.4 MB each
#define PSTR ((size_t)(N_NODES + 1) * 64)                       // ushorts per slab plane

using bf16x8 = __attribute__((ext_vector_type(8))) short;
using f32x4  = __attribute__((ext_vector_type(4))) float;

// float -> bf16 round-to-nearest-even (finite inputs)
static __device__ __forceinline__ unsigned short f2bf(float f) {
  union { float f; unsigned int i; } v; v.f = f;
  unsigned int x = v.i;
  unsigned int r = x + 0x7FFFu + ((x >> 16) & 1u);
  return (unsigned short)(r >> 16);
}
static __device__ __forceinline__ float bf2f(unsigned short u) {
  union { unsigned int i; float f; } v;
  v.i = ((unsigned int)u) << 16;
  return v.f;
}

#define G_TQ    172           // 86 relations x 2 d-blocks
#define G_GEMM  391           // ceil(50000/128)
#define TPAD 136              // 128+8 bf16: 272 B row stride -> 2-way bank alias (free)
#define QPAD 136
#define APAD 136

// ---------------- kernel 0: weight prep + sentinel zeroing + pcnt/mask/bmask/Mcount zero ----------------

__global__ __launch_bounds__(256) void k_prep(const float* __restrict__ W1, const float* __restrict__ W2,
                                              const float* __restrict__ M,
                                              unsigned short* __restrict__ W1th, unsigned short* __restrict__ W1tl,
                                              unsigned short* __restrict__ W2th, unsigned short* __restrict__ W2tl,
                                              unsigned short* __restrict__ Mth,
                                              unsigned short* __restrict__ hs,
                                              unsigned short* __restrict__ hbuf2,
                                              float* __restrict__ dv,
                                              unsigned int* __restrict__ pcnt,
                                              int* __restrict__ mask,
                                              int* __restrict__ bmask,
                                              int* __restrict__ Mcount) {
  int g = blockIdx.x * 256 + threadIdx.x;          // 16384 threads = DIM*DIM
  if (g < NP) pcnt[g] = 0u;                        // partition atomic counters
  #pragma unroll
  for (int q = 0; q < 4; ++q) {                    // zero needed-mask + batch-mask (N+1 entries)
    int idx = g + q * 16384;
    if (idx <= N_NODES) { mask[idx] = 0; bmask[idx] = 0; }
  }
  // zero sentinel rows (gather pads resolve to ZROW; must be 0.0 not garbage/NaN)
  if (g < 32) {                                    // 2 slab planes x 16 ushort4
    ushort4 z = {0, 0, 0, 0};
    ((ushort4*)(hs + (size_t)(g >> 4) * PSTR))[(size_t)ZROW * 16 + (g & 15)] = z;
  }
  if (g >= 32 && g < 64) {                         // hbuf2 row (32 ushort4)
    ushort4 z = {0, 0, 0, 0};
    ((ushort4*)hbuf2)[(size_t)ZROW * 32 + (g - 32)] = z;
  }
  if (g == 64) dv[ZROW] = 0.f;
  if (g == 65) *Mcount = 0;
  int k = g >> 7, n = g & 127;
  int t = n * DIM + k;
  float w1 = W1[g];
  unsigned short h1 = f2bf(w1);
  W1th[t] = h1;
  W1tl[t] = f2bf(w1 - bf2f(h1));
  float w2 = W2[g];
  unsigned short h2 = f2bf(w2);
  W2th[t] = h2;
  W2tl[t] = f2bf(w2 - bf2f(h2));
  Mth[t] = f2bf(M[g]);
}

// ---------------- bmark: seed batch-node masks (runs after prep's zeroing) ----------------

__global__ __launch_bounds__(256) void k_bmark(const int* __restrict__ head, const int* __restrict__ tail,
                                               int* __restrict__ mask, int* __restrict__ bmask) {
  int i = blockIdx.x * 256 + threadIdx.x;          // 4096 threads
  int node = (i < BATCH) ? head[i] : tail[i - BATCH];
  bmask[node] = 1;
  mask[node] = 1;
}

// ---------------- mega1: edge build, ONE LDS atomic per edge (slot saved in regs)
//                         + neighbor marking  ||  decoder TQ  ||  gemm1 (slab-major out) ----------------
// pe entry: (dst & 255) << 17 | src     (src < 50000 < 2^17)

__global__ __launch_bounds__(256) void k_mega1(const int* __restrict__ src, const int* __restrict__ dst,
                                               unsigned int* __restrict__ pcnt,
                                               unsigned int* __restrict__ pe,
                                               const int* __restrict__ bmask,
                                               int* __restrict__ mask,
                                               const float* __restrict__ Rel,
                                               const unsigned short* __restrict__ Mth,
                                               unsigned short* __restrict__ Qbf,
                                               const float* __restrict__ x,
                                               const unsigned short* __restrict__ W1th,
                                               const unsigned short* __restrict__ W1tl,
                                               unsigned short* __restrict__ hs) {
  __shared__ __align__(16) unsigned char smem[64 * TPAD * 2];   // max(hist 784B, Ts 17408B)
  int bid = blockIdx.x;
  union U { uint4 u; bf16x8 h; };

  if (bid < EB) {
    unsigned int* hist = (unsigned int*)smem;
    int t = threadIdx.x;
    if (t < NP) hist[t] = 0u;
    __syncthreads();
    // ---- load edges ONCE into registers; one LDS atomic per edge, slot saved; neighbor-mark ----
    int4 sA[4], dA[4];
    unsigned int slot2[8];                         // 16 u16 slots packed 2-per-u32
    #pragma unroll
    for (int j = 0; j < 4; ++j) {
      int i0 = bid * 4096 + j * 1024 + t * 4;
      if (i0 < N_EDGES) {
        sA[j] = *(const int4*)(src + i0);
        dA[j] = *(const int4*)(dst + i0);
        unsigned int s0 = atomicAdd(&hist[dA[j].x >> 8], 1u);
        unsigned int s1 = atomicAdd(&hist[dA[j].y >> 8], 1u);
        unsigned int s2 = atomicAdd(&hist[dA[j].z >> 8], 1u);
        unsigned int s3 = atomicAdd(&hist[dA[j].w >> 8], 1u);
        slot2[j * 2]     = s0 | (s1 << 16);
        slot2[j * 2 + 1] = s2 | (s3 << 16);
        // neighbor discovery: src of any edge into a batch node is needed for layer 2
        if (bmask[dA[j].x]) mask[sA[j].x] = 1;
        if (bmask[dA[j].y]) mask[sA[j].y] = 1;
        if (bmask[dA[j].z]) mask[sA[j].z] = 1;
        if (bmask[dA[j].w]) mask[sA[j].w] = 1;
      }
    }
    __syncthreads();
    // ---- reserve global ranges: one atomic per (block, bin); hist becomes ABSOLUTE BASE ----
    if (t < NP) {
      unsigned int c = hist[t];
      unsigned int base = c ? atomicAdd(&pcnt[t], c) : 0u;
      hist[t] = (unsigned int)t * PCAP + base;     // read-only below
    }
    __syncthreads();
    // ---- scatter from registers: plain LDS reads + saved slots (no atomics) ----
    #pragma unroll
    for (int j = 0; j < 4; ++j) {
      int i0 = bid * 4096 + j * 1024 + t * 4;
      if (i0 < N_EDGES) {
        int b0 = dA[j].x >> 8, b1 = dA[j].y >> 8, b2 = dA[j].z >> 8, b3 = dA[j].w >> 8;
        unsigned int p0 = hist[b0] + (slot2[j * 2] & 0xFFFFu);
        unsigned int p1 = hist[b1] + (slot2[j * 2] >> 16);
        unsigned int p2 = hist[b2] + (slot2[j * 2 + 1] & 0xFFFFu);
        unsigned int p3 = hist[b3] + (slot2[j * 2 + 1] >> 16);
        if (p0 < (unsigned int)(b0 + 1) * PCAP) pe[p0] = ((unsigned)(dA[j].x & 255) << 17) | (unsigned)sA[j].x;
        if (p1 < (unsigned int)(b1 + 1) * PCAP) pe[p1] = ((unsigned)(dA[j].y & 255) << 17) | (unsigned)sA[j].y;
        if (p2 < (unsigned int)(b2 + 1) * PCAP) pe[p2] = ((unsigned)(dA[j].z & 255) << 17) | (unsigned)sA[j].z;
        if (p3 < (unsigned int)(b3 + 1) * PCAP) pe[p3] = ((unsigned)(dA[j].w & 255) << 17) | (unsigned)sA[j].w;
      }
    }
    return;
  }

  int wave = threadIdx.x >> 6, lane = threadIdx.x & 63;
  int l15 = lane & 15, quad = lane >> 4;

  if (bid < EB + G_TQ) {
    // ---- decoder precompute: T_r = Rel_r @ M (LDS), Q_r = T_r @ Rel_r^T ----
    unsigned short* Ts = (unsigned short*)smem;
    int tb = bid - EB;                       // [0, 172)
    int r = tb >> 1, dblk = tb & 1;
    const float* Rr = Rel + (size_t)r * DIM * DIM;
    unsigned short* Qr = Qbf + (size_t)r * DIM * DIM;
    int dw = dblk * 64 + wave * 16;
    f32x4 acc[8];
    #pragma unroll
    for (int nt = 0; nt < 8; ++nt) acc[nt] = f32x4{0.f, 0.f, 0.f, 0.f};
    #pragma unroll
    for (int ks = 0; ks < 4; ++ks) {
      int k0 = ks * 32 + quad * 8;
      const float* ap = Rr + (size_t)(dw + l15) * DIM + k0;
      float av[8];
      *(float4*)(av)     = *(const float4*)(ap);
      *(float4*)(av + 4) = *(const float4*)(ap + 4);
      bf16x8 a;
      #pragma unroll
      for (int j = 0; j < 8; ++j) a[j] = (short)f2bf(av[j]);
      #pragma unroll
      for (int nt = 0; nt < 8; ++nt) {
        U b; b.u = *(const uint4*)(Mth + (nt * 16 + l15) * DIM + k0);
        acc[nt] = __builtin_amdgcn_mfma_f32_16x16x32_bf16(a, b.h, acc[nt], 0, 0, 0);
      }
    }
    #pragma unroll
    for (int nt = 0; nt < 8; ++nt)
      #pragma unroll
      for (int reg = 0; reg < 4; ++reg)
        Ts[(wave * 16 + quad * 4 + reg) * TPAD + nt * 16 + l15] = f2bf(acc[nt][reg]);
    __syncthreads();
    f32x4 qacc[8];
    #pragma unroll
    for (int nt = 0; nt < 8; ++nt) qacc[nt] = f32x4{0.f, 0.f, 0.f, 0.f};
    #pragma unroll
    for (int ks = 0; ks < 4; ++ks) {
      int k0 = ks * 32 + quad * 8;
      U a; a.u = *(const uint4*)(Ts + (wave * 16 + l15) * TPAD + k0);
      #pragma unroll
      for (int nt = 0; nt < 8; ++nt) {
        const float* bp = Rr + (size_t)(nt * 16 + l15) * DIM + k0;
        float bv[8];
        *(float4*)(bv)     = *(const float4*)(bp);
        *(float4*)(bv + 4) = *(const float4*)(bp + 4);
        bf16x8 b;
        #pragma unroll
        for (int j = 0; j < 8; ++j) b[j] = (short)f2bf(bv[j]);
        qacc[nt] = __builtin_amdgcn_mfma_f32_16x16x32_bf16(a.h, b, qacc[nt], 0, 0, 0);
      }
    }
    #pragma unroll
    for (int nt = 0; nt < 8; ++nt)
      #pragma unroll
      for (int reg = 0; reg < 4; ++reg)
        Qr[(size_t)(dw + quad * 4 + reg) * DIM + nt * 16 + l15] = f2bf(qacc[nt][reg]);
    return;
  }

  // ---- node GEMM layer 1: hs = slab-major(x @ W1) (hi/lo 3-term, bf16 out) ----
  int r0 = (bid - EB - G_TQ) * 128 + wave * 32;
  f32x4 acc[2][8];
  #pragma unroll
  for (int mt = 0; mt < 2; ++mt)
    #pragma unroll
    for (int nt = 0; nt < 8; ++nt) acc[mt][nt] = f32x4{0.f, 0.f, 0.f, 0.f};
  #pragma unroll
  for (int ks = 0; ks < 4; ++ks) {
    int k0 = ks * 32 + quad * 8;
    bf16x8 ah[2], al[2];
    #pragma unroll
    for (int mt = 0; mt < 2; ++mt) {
      int row = r0 + mt * 16 + l15;
      row = (row < N_NODES) ? row : (N_NODES - 1);
      const float* xp = x + (size_t)row * DIM + k0;
      float xv[8];
      *(float4*)(xv)     = *(const float4*)(xp);
      *(float4*)(xv + 4) = *(const float4*)(xp + 4);
      #pragma unroll
      for (int j = 0; j < 8; ++j) {
        unsigned short h = f2bf(xv[j]);
        ah[mt][j] = (short)h;
        al[mt][j] = (short)f2bf(xv[j] - bf2f(h));
      }
    }
    #pragma unroll
    for (int nt = 0; nt < 8; ++nt) {
      U bh, bl;
      bh.u = *(const uint4*)(W1th + (nt * 16 + l15) * DIM + k0);
      bl.u = *(const uint4*)(W1tl + (nt * 16 + l15) * DIM + k0);
      #pragma unroll
      for (int mt = 0; mt < 2; ++mt) {
        acc[mt][nt] = __builtin_amdgcn_mfma_f32_16x16x32_bf16(ah[mt], bh.h, acc[mt][nt], 0, 0, 0);
        acc[mt][nt] = __builtin_amdgcn_mfma_f32_16x16x32_bf16(al[mt], bh.h, acc[mt][nt], 0, 0, 0);
        acc[mt][nt] = __builtin_amdgcn_mfma_f32_16x16x32_bf16(ah[mt], bl.h, acc[mt][nt], 0, 0, 0);
      }
    }
  }
  #pragma unroll
  for (int mt = 0; mt < 2; ++mt)
    #pragma unroll
    for (int reg = 0; reg < 4; ++reg) {
      int row = r0 + mt * 16 + quad * 4 + reg;
      if (row < N_NODES) {
        #pragma unroll
        for (int nt = 0; nt < 8; ++nt)
          hs[(size_t)(nt >> 2) * PSTR + (size_t)row * 64 + (nt & 3) * 16 + l15] = f2bf(acc[mt][nt][reg]);
      }
    }
}

// ---------------- build: per-partition bucket fill (u16) + pad-to-8 + cnt + dinv + fused compact ----------------

__global__ __launch_bounds__(256) void k_build(const unsigned int* __restrict__ pe,
                                               const unsigned int* __restrict__ partCnt,
                                               unsigned short* __restrict__ esrc, int* __restrict__ cnt,
                                               float* __restrict__ dv,
                                               const int* __restrict__ mask,
                                               int* __restrict__ list,
                                               int* __restrict__ Mcount) {
  __shared__ unsigned int c256[256];
  __shared__ int sd[256];
  __shared__ int sbase;
  int p = blockIdx.x, t = threadIdx.x;
  c256[t] = 0u;
  __syncthreads();
  int m = min((int)partCnt[p], PCAP);
  for (int i = t; i < m; i += 256) {
    unsigned int e = pe[(size_t)p * PCAP + i];
    unsigned int local = e >> 17;
    unsigned int s = e & 0x1FFFFu;
    unsigned int slot = atomicAdd(&c256[local], 1u);
    int node = p * 256 + (int)local;
    if (slot < CAP) esrc[(size_t)node * CAP + slot] = (unsigned short)s;
  }
  __syncthreads();
  int node = p * 256 + t;
  if (node < N_NODES) {
    int c = (int)c256[t];
    cnt[node] = c;
    dv[node] = rsqrtf((float)(c + 1));
    int padded = min((c + 7) & ~7, CAP);          // pad bucket to multiple of 8
    for (int s = c; s < padded; ++s) esrc[(size_t)node * CAP + s] = (unsigned short)ZROW;
  }
  // ---- fused compact: needed-mask -> list (block p owns nodes p*256..p*256+255) ----
  int nm = (node < N_NODES) ? mask[node] : 0;
  sd[t] = nm;
  __syncthreads();
  for (int off = 1; off < 256; off <<= 1) {
    int y = (t >= off) ? sd[t - off] : 0;
    __syncthreads();
    sd[t] += y;
    __syncthreads();
  }
  if (t == 255) sbase = atomicAdd(Mcount, sd[255]);
  __syncthreads();
  if (nm) list[sbase + sd[t] - 1] = node;
}

// ---------------- edv: pre-gather per-edge-slot dinv, list-driven ----------------

__global__ __launch_bounds__(256) void k_edv(const int* __restrict__ list,
                                             const int* __restrict__ Mcount,
                                             const unsigned short* __restrict__ esrc,
                                             const int* __restrict__ cnt,
                                             const float* __restrict__ dv,
                                             float* __restrict__ edv) {
  int j = blockIdx.x * 32 + (threadIdx.x >> 3);
  if (j >= *Mcount) return;
  int node = list[j];
  int s0 = (threadIdx.x & 7) * 8;                 // this lane's 8 slots
  int padded = min((cnt[node] + 7) & ~7, CAP);
  if (s0 >= padded) return;                       // garbage slots never read downstream
  const unsigned short* eb = esrc + (size_t)node * CAP + s0;
  ushort4 a = *(const ushort4*)(eb);
  ushort4 b = *(const ushort4*)(eb + 4);
  float4 da, db;
  da.x = dv[min((int)a.x, ZROW)]; da.y = dv[min((int)a.y, ZROW)];
  da.z = dv[min((int)a.z, ZROW)]; da.w = dv[min((int)a.w, ZROW)];
  db.x = dv[min((int)b.x, ZROW)]; db.y = dv[min((int)b.y, ZROW)];
  db.z = dv[min((int)b.z, ZROW)]; db.w = dv[min((int)b.w, ZROW)];
  *(float4*)(edv + (size_t)node * CAP + s0)     = da;
  *(float4*)(edv + (size_t)node * CAP + s0 + 4) = db;
}

// ---------------- fused agg1 + gemm2: LIST-DRIVEN, 16 nodes/block; 32 lanes/node
//                  (16 per slab plane); each edge visited once; MFMA @ W2 from LDS ----------------

__global__ __launch_bounds__(256) void k_agg_gemm2(const unsigned short* __restrict__ hs,
                                                   const int* __restrict__ cnt,
                                                   const float* __restrict__ dv,
                                                   const unsigned short* __restrict__ esrc,
                                                   const float* __restrict__ edv,
                                                   const float* __restrict__ bias,
                                                   const unsigned short* __restrict__ Wth,
                                                   const unsigned short* __restrict__ Wtl,
                                                   const int* __restrict__ list,
                                                   const int* __restrict__ Mcount,
                                                   unsigned short* __restrict__ out) {
  __shared__ __align__(16) unsigned short Ah[16 * APAD];
  __shared__ __align__(16) unsigned short Al[16 * APAD];
  __shared__ int nodeIds[16];
  int Mn = *Mcount;
  int base = blockIdx.x * 16;
  if (base >= Mn) return;
  if (threadIdx.x < 16) {
    int j = base + threadIdx.x;
    nodeIds[threadIdx.x] = (j < Mn) ? list[j] : ZROW;
  }
  __syncthreads();

  int warp = threadIdx.x >> 5, lane32 = threadIdx.x & 31;
  int half = lane32 >> 4, lane16 = lane32 & 15;   // half selects slab plane
  const ushort4* h4 = (const ushort4*)(hs + (size_t)half * PSTR);   // 16 ushort4 per row-slab

  #pragma unroll
  for (int i = 0; i < 2; ++i) {
    int row = warp * 2 + i;
    int node = nodeIds[row];
    if (node == ZROW) {                           // boundary pad: keep LDS defined, skip work
      ushort4 z = {0, 0, 0, 0};
      *(ushort4*)(&Ah[row * APAD + lane32 * 4]) = z;
      *(ushort4*)(&Al[row * APAD + lane32 * 4]) = z;
      continue;
    }
    int deg = cnt[node];
    int end = min((deg + 7) & ~7, CAP);           // padded multiple of 8
    float di = dv[node];
    ushort4 hv = h4[(size_t)node * 16 + lane16];
    float ax = di * bf2f(hv.x), ay = di * bf2f(hv.y), az = di * bf2f(hv.z), aw = di * bf2f(hv.w);
    float bx = 0.f, by = 0.f, bz = 0.f, bw = 0.f;
    const unsigned short* eb = esrc + (size_t)node * CAP;
    const float* ev = edv + (size_t)node * CAP;
    for (int e = 0; e < end; e += 8) {
      ushort4 iA = *(const ushort4*)(eb + e);     // broadcast within 32-lane group
      ushort4 iB = *(const ushort4*)(eb + e + 4);
      float4 dA = *(const float4*)(ev + e);       // sequential, broadcast within group
      float4 dB = *(const float4*)(ev + e + 4);
      ushort4 v0 = h4[(size_t)iA.x * 16 + lane16];
      ushort4 v1 = h4[(size_t)iA.y * 16 + lane16];
      ushort4 v2 = h4[(size_t)iA.z * 16 + lane16];
      ushort4 v3 = h4[(size_t)iA.w * 16 + lane16];
      ushort4 v4 = h4[(size_t)iB.x * 16 + lane16];
      ushort4 v5 = h4[(size_t)iB.y * 16 + lane16];
      ushort4 v6 = h4[(size_t)iB.z * 16 + lane16];
      ushort4 v7 = h4[(size_t)iB.w * 16 + lane16];
      ax = fmaf(dA.x, bf2f(v0.x), ax); ay = fmaf(dA.x, bf2f(v0.y), ay); az = fmaf(dA.x, bf2f(v0.z), az); aw = fmaf(dA.x, bf2f(v0.w), aw);
      bx = fmaf(dA.y, bf2f(v1.x), bx); by = fmaf(dA.y, bf2f(v1.y), by); bz = fmaf(dA.y, bf2f(v1.z), bz); bw = fmaf(dA.y, bf2f(v1.w), bw);
      ax = fmaf(dA.z, bf2f(v2.x), ax); ay = fmaf(dA.z, bf2f(v2.y), ay); az = fmaf(dA.z, bf2f(v2.z), az); aw = fmaf(dA.z, bf2f(v2.w), aw);
      bx = fmaf(dA.w, bf2f(v3.x), bx); by = fmaf(dA.w, bf2f(v3.y), by); bz = fmaf(dA.w, bf2f(v3.z), bz); bw = fmaf(dA.w, bf2f(v3.w), bw);
      ax = fmaf(dB.x, bf2f(v4.x), ax); ay = fmaf(dB.x, bf2f(v4.y), ay); az = fmaf(dB.x, bf2f(v4.z), az); aw = fmaf(dB.x, bf2f(v4.w), aw);
      bx = fmaf(dB.y, bf2f(v5.x), bx); by = fmaf(dB.y, bf2f(v5.y), by); bz = fmaf(dB.y, bf2f(v5.z), bz); bw = fmaf(dB.y, bf2f(v5.w), bw);
      ax = fmaf(dB.z, bf2f(v6.x), ax); ay = fmaf(dB.z, bf2f(v6.y), ay); az = fmaf(dB.z, bf2f(v6.z), az); aw = fmaf(dB.z, bf2f(v6.w), aw);
      bx = fmaf(dB.w, bf2f(v7.x), bx); by = fmaf(dB.w, bf2f(v7.y), by); bz = fmaf(dB.w, bf2f(v7.z), bz); bw = fmaf(dB.w, bf2f(v7.w), bw);
    }
    ax += bx; ay += by; az += bz; aw += bw;
    float4 bb = ((const float4*)bias)[lane32];    // dims lane32*4..+3 = half*64 + lane16*4
    float vx = fmaf(di, ax, bb.x), vy = fmaf(di, ay, bb.y);
    float vz = fmaf(di, az, bb.z), vw = fmaf(di, aw, bb.w);
    ushort4 hi4, lo4;
    hi4.x = f2bf(vx); lo4.x = f2bf(vx - bf2f(hi4.x));
    hi4.y = f2bf(vy); lo4.y = f2bf(vy - bf2f(hi4.y));
    hi4.z = f2bf(vz); lo4.z = f2bf(vz - bf2f(hi4.z));
    hi4.w = f2bf(vw); lo4.w = f2bf(vw - bf2f(hi4.w));
    *(ushort4*)(&Ah[row * APAD + lane32 * 4]) = hi4;
    *(ushort4*)(&Al[row * APAD + lane32 * 4]) = lo4;
  }
  __syncthreads();

  // GEMM phase: 4 wave64s, each computes rows 0..15 x cols [wave*32, wave*32+32)
  int wave = threadIdx.x >> 6, l = threadIdx.x & 63;
  int l15 = l & 15, quad = l >> 4;
  union U { uint4 u; bf16x8 h; };
  f32x4 acc[2];
  #pragma unroll
  for (int nt = 0; nt < 2; ++nt) acc[nt] = f32x4{0.f, 0.f, 0.f, 0.f};
  #pragma unroll
  for (int ks = 0; ks < 4; ++ks) {
    int k0 = ks * 32 + quad * 8;
    U ah, al;
    ah.u = *(const uint4*)(&Ah[l15 * APAD + k0]);
    al.u = *(const uint4*)(&Al[l15 * APAD + k0]);
    #pragma unroll
    for (int nt = 0; nt < 2; ++nt) {
      int n0 = wave * 32 + nt * 16;
      U bh, bl;
      bh.u = *(const uint4*)(Wth + (n0 + l15) * DIM + k0);
      bl.u = *(const uint4*)(Wtl + (n0 + l15) * DIM + k0);
      acc[nt] = __builtin_amdgcn_mfma_f32_16x16x32_bf16(ah.h, bh.h, acc[nt], 0, 0, 0);
      acc[nt] = __builtin_amdgcn_mfma_f32_16x16x32_bf16(al.h, bh.h, acc[nt], 0, 0, 0);
      acc[nt] = __builtin_amdgcn_mfma_f32_16x16x32_bf16(ah.h, bl.h, acc[nt], 0, 0, 0);
    }
  }
  #pragma unroll
  for (int reg = 0; reg < 4; ++reg) {
    int node = nodeIds[quad * 4 + reg];
    if (node != ZROW) {                           // keep hbuf2[ZROW] zeroed for pads
      #pragma unroll
      for (int nt = 0; nt < 2; ++nt)
        out[(size_t)node * DIM + wave * 32 + nt * 16 + l15] = f2bf(acc[nt][reg]);
    }
  }
}

// ---------------- full-row aggregation core (agg_batch; hbuf2 row-major, sequential edv) ----------------

static __device__ __forceinline__ float4 agg_compute(const unsigned short* __restrict__ h,
                                                     const int* __restrict__ cnt,
                                                     const float* __restrict__ dv,
                                                     const unsigned short* __restrict__ esrc,
                                                     const float* __restrict__ edv,
                                                     const float* __restrict__ bias,
                                                     int node, int lane) {
  const ushort4* h4 = (const ushort4*)h;
  int deg = cnt[node];
  int end = min((deg + 7) & ~7, CAP);              // padded length, multiple of 8
  float di = dv[node];
  ushort4 hv = h4[(size_t)node * 32 + lane];
  float ax = di * bf2f(hv.x), ay = di * bf2f(hv.y), az = di * bf2f(hv.z), aw = di * bf2f(hv.w);
  float bx = 0.f, by = 0.f, bz = 0.f, bw = 0.f;
  const unsigned short* eb = esrc + (size_t)node * CAP;
  const float* ev = edv + (size_t)node * CAP;
  for (int e = 0; e < end; e += 8) {
    ushort4 iA = *(const ushort4*)(eb + e);
    ushort4 iB = *(const ushort4*)(eb + e + 4);
    float4 dA = *(const float4*)(ev + e);
    float4 dB = *(const float4*)(ev + e + 4);
    ushort4 v0 = h4[(size_t)iA.x * 32 + lane];
    ushort4 v1 = h4[(size_t)iA.y * 32 + lane];
    ushort4 v2 = h4[(size_t)iA.z * 32 + lane];
    ushort4 v3 = h4[(size_t)iA.w * 32 + lane];
    ushort4 v4 = h4[(size_t)iB.x * 32 + lane];
    ushort4 v5 = h4[(size_t)iB.y * 32 + lane];
    ushort4 v6 = h4[(size_t)iB.z * 32 + lane];
    ushort4 v7 = h4[(size_t)iB.w * 32 + lane];
    ax = fmaf(dA.x, bf2f(v0.x), ax); ay = fmaf(dA.x, bf2f(v0.y), ay); az = fmaf(dA.x, bf2f(v0.z), az); aw = fmaf(dA.x, bf2f(v0.w), aw);
    bx = fmaf(dA.y, bf2f(v1.x), bx); by = fmaf(dA.y, bf2f(v1.y), by); bz = fmaf(dA.y, bf2f(v1.z), bz); bw = fmaf(dA.y, bf2f(v1.w), bw);
    ax = fmaf(dA.z, bf2f(v2.x), ax); ay = fmaf(dA.z, bf2f(v2.y), ay); az = fmaf(dA.z, bf2f(v2.z), az); aw = fmaf(dA.z, bf2f(v2.w), aw);
    bx = fmaf(dA.w, bf2f(v3.x), bx); by = fmaf(dA.w, bf2f(v3.y), by); bz = fmaf(dA.w, bf2f(v3.z), bz); bw = fmaf(dA.w, bf2f(v3.w), bw);
    ax = fmaf(dB.x, bf2f(v4.x), ax); ay = fmaf(dB.x, bf2f(v4.y), ay); az = fmaf(dB.x, bf2f(v4.z), az); aw = fmaf(dB.x, bf2f(v4.w), aw);
    bx = fmaf(dB.y, bf2f(v5.x), bx); by = fmaf(dB.y, bf2f(v5.y), by); bz = fmaf(dB.y, bf2f(v5.z), bz); bw = fmaf(dB.y, bf2f(v5.w), bw);
    ax = fmaf(dB.z, bf2f(v6.x), ax); ay = fmaf(dB.z, bf2f(v6.y), ay); az = fmaf(dB.z, bf2f(v6.z), az); aw = fmaf(dB.z, bf2f(v6.w), aw);
    bx = fmaf(dB.w, bf2f(v7.x), bx); by = fmaf(dB.w, bf2f(v7.y), by); bz = fmaf(dB.w, bf2f(v7.z), bz); bw = fmaf(dB.w, bf2f(v7.w), bw);
  }
  ax += bx; ay += by; az += bz; aw += bw;
  float4 bb = ((const float4*)bias)[lane];
  float4 v;
  v.x = fmaf(di, ax, bb.x); v.y = fmaf(di, ay, bb.y);
  v.z = fmaf(di, az, bb.z); v.w = fmaf(di, aw, bb.w);
  return v;
}

// ---------------- agg2 at batch positions only ----------------
// head rows -> fp32 plane pf[BATCH][128]; tail rows -> bf16 hi plane pth[BATCH][128]

__global__ __launch_bounds__(256) void k_agg_batch(const unsigned short* __restrict__ h,
                                                   const int* __restrict__ cnt,
                                                   const float* __restrict__ dv,
                                                   const unsigned short* __restrict__ esrc,
                                                   const float* __restrict__ edv,
                                                   const float* __restrict__ bias,
                                                   const int* __restrict__ head,
                                                   const int* __restrict__ tail,
                                                   float* __restrict__ pf,
                                                   unsigned short* __restrict__ pth) {
  int pos = blockIdx.x * 8 + (threadIdx.x >> 5);
  if (pos >= 2 * BATCH) return;
  int lane = threadIdx.x & 31;
  int node = (pos < BATCH) ? head[pos] : tail[pos - BATCH];
  float4 v = agg_compute(h, cnt, dv, esrc, edv, bias, node, lane);
  if (pos < BATCH) {
    ((float4*)pf)[(size_t)pos * 32 + lane] = v;
  } else {
    ushort4 hi4 = { f2bf(v.x), f2bf(v.y), f2bf(v.z), f2bf(v.w) };
    ((ushort4*)pth)[(size_t)(pos - BATCH) * 32 + lane] = hi4;
  }
}

// ---------------- predict via MFMA: tail (bf16) @ Q_r, dot with head (fp32) ----------------

__global__ __launch_bounds__(256) void k_predict_mfma(const float* __restrict__ pf,
                                                      const unsigned short* __restrict__ pth,
                                                      const unsigned short* __restrict__ Qbf,
                                                      float* __restrict__ out) {
  __shared__ __align__(16) unsigned short Qs[DIM * QPAD];
  int r = blockIdx.y;
  const unsigned short* Qr = Qbf + (size_t)r * DIM * DIM;
  for (int i = threadIdx.x; i < DIM * DIM / 8; i += 256) {
    int d = i >> 4, c = (i & 15) * 8;
    uint4 v = ((const uint4*)Qr)[i];
    *(uint4*)(&Qs[d * QPAD + c]) = v;
  }
  __syncthreads();
  int wave = threadIdx.x >> 6, lane = threadIdx.x & 63;
  int l15 = lane & 15, quad = lane >> 4;
  int bbase = blockIdx.x * 128 + wave * 32;
  int t0 = bbase + l15;                    // tail plane rows (coalesced, no gather)
  int t1 = bbase + 16 + l15;

  f32x4 acc[2][8];
  #pragma unroll
  for (int m = 0; m < 2; ++m)
    #pragma unroll
    for (int n = 0; n < 8; ++n) acc[m][n] = f32x4{0.f, 0.f, 0.f, 0.f};

  union U { uint4 u; bf16x8 h; };
  #pragma unroll
  for (int ks = 0; ks < 4; ++ks) {
    int eoff = ks * 32 + quad * 8;
    U a0, a1;
    a0.u = *(const uint4*)(pth + (size_t)t0 * DIM + eoff);
    a1.u = *(const uint4*)(pth + (size_t)t1 * DIM + eoff);
    #pragma unroll
    for (int nt = 0; nt < 8; ++nt) {
      U b; b.u = *(const uint4*)(&Qs[(nt * 16 + l15) * QPAD + eoff]);
      acc[0][nt] = __builtin_amdgcn_mfma_f32_16x16x32_bf16(a0.h, b.h, acc[0][nt], 0, 0, 0);
      acc[1][nt] = __builtin_amdgcn_mfma_f32_16x16x32_bf16(a1.h, b.h, acc[1][nt], 0, 0, 0);
    }
  }

  #pragma unroll
  for (int m = 0; m < 2; ++m) {
    #pragma unroll
    for (int reg = 0; reg < 4; ++reg) {
      int bl = bbase + m * 16 + quad * 4 + reg;             // batch index == head plane row
      float s = 0.f;
      #pragma unroll
      for (int nt = 0; nt < 8; ++nt)
        s += pf[(size_t)bl * DIM + nt * 16 + l15] * acc[m][nt][reg];   // head = fp32 plane
      #pragma unroll
      for (int off = 1; off < 16; off <<= 1) s += __shfl_xor(s, off, 64);
      if (l15 == 0) out[(size_t)bl * N_REL + r] = s;
    }
  }
}

// ---------------- launch ----------------

extern "C" void kernel_launch(void* const* d_in, const int* in_sizes, int n_in,
                              void* d_out, int out_size, void* d_ws, size_t ws_size,
                              hipStream_t stream) {
  (void)in_sizes; (void)n_in; (void)out_size; (void)ws_size;
  const float* init_emb = (const float*)d_in[0];
  const float* W1  = (const float*)d_in[1];
  const float* b1  = (const float*)d_in[2];
  const float* W2  = (const float*)d_in[3];
  const float* b2  = (const float*)d_in[4];
  const float* Rel = (const float*)d_in[5];
  const float* M   = (const float*)d_in[6];
  const int* head  = (const int*)d_in[7];
  const int* tail  = (const int*)d_in[8];
  const int* src   = (const int*)d_in[9];
  const int* dst   = src + N_EDGES;
  float* out = (float*)d_out;

  char* p = (char*)d_ws;
  auto alloc = [&](size_t bytes) { char* q = p; p += (bytes + 511) & ~(size_t)511; return q; };
  unsigned int* pcnt = (unsigned int*)alloc((size_t)NP * 4);                   // atomic partition counters
  unsigned int* pe = (unsigned int*)alloc((size_t)NP * PCAP * 4);              // 6.4 MB packed edges
  int*   cnt  = (int*)alloc((size_t)N_NODES * 4);
  float* dv   = (float*)alloc((size_t)(N_NODES + 1) * 4);                      // +1 sentinel
  int*   mask = (int*)alloc((size_t)(N_NODES + 1) * 4);                        // needed-node mask
  int*   bmask = (int*)alloc((size_t)(N_NODES + 1) * 4);                       // batch-node mask (read-only in mega1)
  int*   list = (int*)alloc((size_t)N_NODES * 4);                              // compacted needed nodes
  int*   Mcount = (int*)alloc(64);
  unsigned short* esrc = (unsigned short*)alloc((size_t)N_NODES * CAP * 2);    // 6.4 MB u16 buckets
  float* edv = (float*)alloc((size_t)N_NODES * CAP * 4);                       // 12.8 MB per-slot dinv
  unsigned short* hs    = (unsigned short*)alloc((size_t)NSLAB * PSTR * 2);    // slab-major h1 (+zero row)
  unsigned short* hbuf2 = (unsigned short*)alloc((size_t)(N_NODES + 1) * DIM * 2);  // +1 zero row
  float*          pf    = (float*)alloc((size_t)BATCH * DIM * 4);              // head plane fp32
  unsigned short* pth   = (unsigned short*)alloc((size_t)BATCH * DIM * 2);     // tail plane bf16 hi
  unsigned short* Qbf   = (unsigned short*)alloc((size_t)N_REL * DIM * DIM * 2);
  unsigned short* W1th  = (unsigned short*)alloc((size_t)DIM * DIM * 2);
  unsigned short* W1tl  = (unsigned short*)alloc((size_t)DIM * DIM * 2);
  unsigned short* W2th  = (unsigned short*)alloc((size_t)DIM * DIM * 2);
  unsigned short* W2tl  = (unsigned short*)alloc((size_t)DIM * DIM * 2);
  unsigned short* Mth   = (unsigned short*)alloc((size_t)DIM * DIM * 2);

  // 0: weight prep + sentinel zeroing + pcnt/mask/bmask/Mcount zero
  k_prep<<<DIM * DIM / 256, 256, 0, stream>>>(W1, W2, M, W1th, W1tl, W2th, W2tl, Mth,
                                              hs, hbuf2, dv, pcnt, mask, bmask, Mcount);
  // 1: seed batch-node masks
  k_bmark<<<2 * BATCH / 256, 256, 0, stream>>>(head, tail, mask, bmask);
  // 2: edge build (1 LDS atomic/edge, slots in regs, inline neighbor marking) || decoder TQ || gemm1
  k_mega1<<<EB + G_TQ + G_GEMM, 256, 0, stream>>>(src, dst, pcnt, pe, bmask, mask, Rel, Mth, Qbf,
                                                  init_emb, W1th, W1tl, hs);
  // 3: per-partition bucket fill -> esrc + cnt + dinv + fused compact (mask -> list)
  k_build<<<NP, 256, 0, stream>>>(pe, pcnt, esrc, cnt, dv, mask, list, Mcount);
  // 4: pre-gather per-slot dinv -> edv (list-driven)
  k_edv<<<(N_NODES + 31) / 32, 256, 0, stream>>>(list, Mcount, esrc, cnt, dv, edv);
  // 5: fused agg1 + gemm2 (list-driven; both slab planes; MFMA from LDS)
  k_agg_gemm2<<<(N_NODES + 15) / 16, 256, 0, stream>>>(hs, cnt, dv, esrc, edv, b1, W2th, W2tl,
                                                       list, Mcount, hbuf2);
  // 6: agg2 only at batch positions -> compact planes (head fp32, tail bf16)
  k_agg_batch<<<(2 * BATCH + 7) / 8, 256, 0, stream>>>(hbuf2, cnt, dv, esrc, edv, b2, head, tail, pf, pth);
  // 7: predict (coalesced reads from compact planes)
  k_predict_mfma<<<dim3(BATCH / 128, N_REL), 256, 0, stream>>>(pf, pth, Qbf, out);
}